// Round 14
// baseline (252.853 us; speedup 1.0000x reference)
//
#include <hip/hip_runtime.h>

#define N_NODES 50000
#define N_PAD   50048   // 782 * 64
#define N_EDGES 800000
#define N_GRAPHS 512
#define F_IN 96
#define HID 128
#define NBUCK 196       // buckets of 256 nodes (dst >> 8)
#define CHUNK 8192      // edges per chunk block
#define NCH   98        // ceil(800000/8192)
#define NB_G 782        // gemm blocks (N_PAD/64)

typedef __bf16 bf16x8 __attribute__((ext_vector_type(8)));
typedef float  f32x4  __attribute__((ext_vector_type(4)));

__device__ __forceinline__ unsigned short f2bf(float f) {
    union { float f; unsigned u; } v; v.f = f;
    unsigned r = v.u + 0x7FFFu + ((v.u >> 16) & 1u);  // RNE
    return (unsigned short)(r >> 16);
}
__device__ __forceinline__ float bflo(unsigned u) {
    union { unsigned u; float f; } v; v.u = u << 16; return v.f;
}
__device__ __forceinline__ float bfhi(unsigned u) {
    union { unsigned u; float f; } v; v.u = u & 0xFFFF0000u; return v.f;
}

// build one B-fragment entry (8 bf16 = uint4) from f32 W[K x 128]
__device__ __forceinline__ uint4 frag_of(const float* __restrict__ W, int KS, int idx) {
    int t = idx / (KS * 64);
    int rem = idx % (KS * 64);
    int s = rem / 64;
    int l = rem & 63;
    int n = t * 16 + (l & 15);
    int k0 = s * 32 + (l >> 4) * 8;
    unsigned short v[8];
#pragma unroll
    for (int j = 0; j < 8; ++j) v[j] = f2bf(W[(long)(k0 + j) * 128 + n]);
    uint4 o;
    o.x = (unsigned)v[0] | ((unsigned)v[1] << 16);
    o.y = (unsigned)v[2] | ((unsigned)v[3] << 16);
    o.z = (unsigned)v[4] | ((unsigned)v[5] << 16);
    o.w = (unsigned)v[6] | ((unsigned)v[7] << 16);
    return o;
}

// ---- K1: gemm1-raw (0..781)  ||  chunk hists (782..879)  ||  W2 prep (880..887) ----
__global__ __launch_bounds__(256) void k1_fused(const int* __restrict__ dst,
                                                const float* __restrict__ W1,
                                                const float* __restrict__ W2,
                                                unsigned short* __restrict__ W2f,
                                                int* __restrict__ bh,
                                                const float* __restrict__ x,
                                                unsigned short* __restrict__ hp) {
    __shared__ uint4 w1lds[1536];  // 24 KB (aliased as hist for hist blocks)
    int blk = blockIdx.x;
    int tid = threadIdx.x;

    if (blk < NB_G) {
        for (int idx = tid; idx < 1536; idx += 256) w1lds[idx] = frag_of(W1, 3, idx);
        __syncthreads();

        const int KS = 3;
        const int wave = tid >> 6, lane = tid & 63;
        const int r0 = blk * 64 + wave * 16;
        f32x4 acc[8];
#pragma unroll
        for (int t = 0; t < 8; ++t) acc[t] = (f32x4){0.f, 0.f, 0.f, 0.f};
        int arow = r0 + (lane & 15);
        if (arow >= N_NODES) arow = N_NODES - 1;  // clamp; pad rows discarded on store
        const int kq = (lane >> 4) * 8;
        for (int s = 0; s < KS; ++s) {
            const float* ap = x + (long)arow * F_IN + s * 32 + kq;
            float4 a0 = *(const float4*)(ap);
            float4 a1 = *(const float4*)(ap + 4);
            union { uint4 u; bf16x8 b; } af;
            af.u.x = (unsigned)f2bf(a0.x) | ((unsigned)f2bf(a0.y) << 16);
            af.u.y = (unsigned)f2bf(a0.z) | ((unsigned)f2bf(a0.w) << 16);
            af.u.z = (unsigned)f2bf(a1.x) | ((unsigned)f2bf(a1.y) << 16);
            af.u.w = (unsigned)f2bf(a1.z) | ((unsigned)f2bf(a1.w) << 16);
#pragma unroll
            for (int t = 0; t < 8; ++t) {
                union { uint4 u; bf16x8 b; } bfr;
                bfr.u = w1lds[(t * KS + s) * 64 + lane];
                acc[t] = __builtin_amdgcn_mfma_f32_16x16x32_bf16(af.b, bfr.b, acc[t], 0, 0, 0);
            }
        }
        const int q = lane >> 4;
#pragma unroll
        for (int t = 0; t < 8; ++t) {
            int col = t * 16 + (lane & 15);
#pragma unroll
            for (int r = 0; r < 4; ++r) {
                int row = r0 + q * 4 + r;
                if (row < N_NODES) hp[(long)row * 128 + col] = f2bf(acc[t][r]);
            }
        }
    } else if (blk < NB_G + NCH) {
        int* bhist = (int*)w1lds;
        int c = blk - NB_G;
        for (int i = tid; i < NBUCK; i += 256) bhist[i] = 0;
        __syncthreads();
        int e0 = c * CHUNK, e1 = min(e0 + CHUNK, N_EDGES);
        int n4 = (e1 - e0) >> 2;  // chunk sizes divisible by 4
        const uint4* d4 = (const uint4*)(dst + e0);
        for (int i = tid; i < n4; i += 256) {
            uint4 d = d4[i];
            atomicAdd(&bhist[d.x >> 8], 1);
            atomicAdd(&bhist[d.y >> 8], 1);
            atomicAdd(&bhist[d.z >> 8], 1);
            atomicAdd(&bhist[d.w >> 8], 1);
        }
        __syncthreads();
        for (int i = tid; i < NBUCK; i += 256) bh[c * NBUCK + i] = bhist[i];
    } else {
        int idx = (blk - NB_G - NCH) * 256 + tid;  // 8 blocks x 256 = 2048 = 8*4*64
        *(uint4*)(W2f + (long)idx * 8) = frag_of(W2, 4, idx);
    }
}

// ---- K2: per-bucket scan over chunks (196 independent scans) ----
__global__ __launch_bounds__(256) void goff_scan(const int* __restrict__ bh,
                                                 int* __restrict__ goff,
                                                 int* __restrict__ total) {
    __shared__ int s[256];
    int b = blockIdx.x;
    int c = threadIdx.x;
    int v = (c < NCH) ? bh[c * NBUCK + b] : 0;
    s[c] = v;
    __syncthreads();
#pragma unroll
    for (int off = 1; off < 256; off <<= 1) {
        int t = 0;
        if (c >= off) t = s[c - off];
        __syncthreads();
        if (c >= off) s[c] += t;
        __syncthreads();
    }
    if (c < NCH) goff[c * NBUCK + b] = s[c] - v;  // exclusive (relative to bucket base)
    if (c == 255) total[b] = s[255];
}

// ---- K3: scatter pairs; bstart derived in-block from total[] ----
__global__ __launch_bounds__(256) void scatter_pairs(const int* __restrict__ src,
                                                     const int* __restrict__ dst,
                                                     const int* __restrict__ goff,
                                                     const int* __restrict__ total,
                                                     uint2* __restrict__ ebuf) {
    __shared__ int ts[256];
    __shared__ int lgoff[NBUCK];
    __shared__ int lcur[NBUCK];
    int tid = threadIdx.x;
    int c = blockIdx.x;
    int tv = (tid < NBUCK) ? total[tid] : 0;
    ts[tid] = tv;
    __syncthreads();
#pragma unroll
    for (int off = 1; off < 256; off <<= 1) {
        int t = 0;
        if (tid >= off) t = ts[tid - off];
        __syncthreads();
        if (tid >= off) ts[tid] += t;
        __syncthreads();
    }
    if (tid < NBUCK) {
        lgoff[tid] = goff[c * NBUCK + tid] + (ts[tid] - tv);  // + bstart[tid]
        lcur[tid] = 0;
    }
    __syncthreads();
    int e0 = c * CHUNK, e1 = min(e0 + CHUNK, N_EDGES);
    for (int e = e0 + tid; e < e1; e += 256) {
        int d = dst[e];
        int b = d >> 8;
        int slot = atomicAdd(&lcur[b], 1);
        ebuf[lgoff[b] + slot] = make_uint2((unsigned)src[e], (unsigned)d);
    }
}

// ---- K4: bucket sort; r0/r1 derived in-block from total[] ----
__global__ __launch_bounds__(256) void bucket_sort(const uint2* __restrict__ ebuf,
                                                   const int* __restrict__ total,
                                                   int* __restrict__ rowstart,
                                                   int* __restrict__ cnt,
                                                   float* __restrict__ dinv,
                                                   int* __restrict__ esrc) {
    __shared__ int ts[256];
    __shared__ int lcnt[256];
    __shared__ int ssc[256];
    __shared__ int ncur[256];
    int b = blockIdx.x, tid = threadIdx.x;
    int tv = (tid < NBUCK) ? total[tid] : 0;
    ts[tid] = tv;
    __syncthreads();
#pragma unroll
    for (int off = 1; off < 256; off <<= 1) {
        int t = 0;
        if (tid >= off) t = ts[tid - off];
        __syncthreads();
        if (tid >= off) ts[tid] += t;
        __syncthreads();
    }
    int r1 = ts[b];
    int r0 = r1 - total[b];
    int nbase = b * 256;
    lcnt[tid] = 0;
    __syncthreads();
    for (int i = r0 + tid; i < r1; i += 256)
        atomicAdd(&lcnt[(int)ebuf[i].y - nbase], 1);
    __syncthreads();
    int c = lcnt[tid];
    ssc[tid] = c;
    __syncthreads();
#pragma unroll
    for (int off = 1; off < 256; off <<= 1) {
        int t = 0;
        if (tid >= off) t = ssc[tid - off];
        __syncthreads();
        if (tid >= off) ssc[tid] += t;
        __syncthreads();
    }
    int rs = r0 + ssc[tid] - c;
    ncur[tid] = rs;
    int node = nbase + tid;
    if (node < N_NODES) {
        rowstart[node] = rs;
        cnt[node] = c;
        dinv[node] = rsqrtf((float)c + 1.0f);
    }
    __syncthreads();
    for (int i = r0 + tid; i < r1; i += 256) {
        uint2 p = ebuf[i];
        int pos = atomicAdd(&ncur[(int)p.y - nbase], 1);
        esrc[pos] = (int)p.x;
    }
}

// ---- K5: aggregate layer 1 — hp RAW; 8 gathers in flight; dinv folded ----
__global__ __launch_bounds__(256) void aggregate_w(const uint4* __restrict__ hp4,
                                                   const int* __restrict__ esrc,
                                                   const int* __restrict__ rowstart,
                                                   const int* __restrict__ cnt,
                                                   const float* __restrict__ dinv,
                                                   const float* __restrict__ bias,
                                                   uint4* __restrict__ hout4) {
    int node = blockIdx.x * 4 + (threadIdx.x >> 6);
    if (node >= N_NODES) return;
    int lane = threadIdx.x & 63;
    int eslot = lane >> 4;
    int ug = lane & 15;
    int start = rowstart[node];
    int end = start + cnt[node];

    float a[8];
#pragma unroll
    for (int k = 0; k < 8; ++k) a[k] = 0.f;

    for (int j = start; j < end; j += 32) {
        int e[8];
        uint4 v[8];
        float w[8];
#pragma unroll
        for (int q = 0; q < 8; ++q) {
            e[q] = j + q * 4 + eslot;
            int s = esrc[min(e[q], end - 1)];
            v[q] = hp4[(long)s * 16 + ug];
            w[q] = dinv[s];
        }
#pragma unroll
        for (int q = 0; q < 8; ++q) {
            if (e[q] < end) {
                a[0] += w[q] * bflo(v[q].x); a[1] += w[q] * bfhi(v[q].x);
                a[2] += w[q] * bflo(v[q].y); a[3] += w[q] * bfhi(v[q].y);
                a[4] += w[q] * bflo(v[q].z); a[5] += w[q] * bfhi(v[q].z);
                a[6] += w[q] * bflo(v[q].w); a[7] += w[q] * bfhi(v[q].w);
            }
        }
    }

#pragma unroll
    for (int k = 0; k < 8; ++k) {
        a[k] += __shfl_xor(a[k], 16);
        a[k] += __shfl_xor(a[k], 32);
    }

    if (eslot == 0) {
        float d = dinv[node];
        uint4 vs = hp4[(long)node * 16 + ug];
        a[0] += d * bflo(vs.x); a[1] += d * bfhi(vs.x);
        a[2] += d * bflo(vs.y); a[3] += d * bfhi(vs.y);
        a[4] += d * bflo(vs.z); a[5] += d * bfhi(vs.z);
        a[6] += d * bflo(vs.w); a[7] += d * bfhi(vs.w);
        float4 b0 = *(const float4*)(bias + ug * 8);
        float4 b1 = *(const float4*)(bias + ug * 8 + 4);
        float o0 = fmaxf(d * a[0] + b0.x, 0.f), o1 = fmaxf(d * a[1] + b0.y, 0.f);
        float o2 = fmaxf(d * a[2] + b0.z, 0.f), o3 = fmaxf(d * a[3] + b0.w, 0.f);
        float o4 = fmaxf(d * a[4] + b1.x, 0.f), o5 = fmaxf(d * a[5] + b1.y, 0.f);
        float o6 = fmaxf(d * a[6] + b1.z, 0.f), o7 = fmaxf(d * a[7] + b1.w, 0.f);
        uint4 o;
        o.x = (unsigned)f2bf(o0) | ((unsigned)f2bf(o1) << 16);
        o.y = (unsigned)f2bf(o2) | ((unsigned)f2bf(o3) << 16);
        o.z = (unsigned)f2bf(o4) | ((unsigned)f2bf(o5) << 16);
        o.w = (unsigned)f2bf(o6) | ((unsigned)f2bf(o7) << 16);
        hout4[(long)node * 16 + ug] = o;
    }
}

// ---- K6: gemm layer 2: hp = bf16(dinv * (h @ W2)) ----
__global__ __launch_bounds__(256) void gemm_mfma_bf16A(const unsigned short* __restrict__ A,
                                                       const unsigned short* __restrict__ Wf,
                                                       const float* __restrict__ dinv,
                                                       unsigned short* __restrict__ hp) {
    const int KS = 4;
    const int wave = threadIdx.x >> 6;
    const int lane = threadIdx.x & 63;
    const int r0 = blockIdx.x * 64 + wave * 16;

    f32x4 acc[8];
#pragma unroll
    for (int t = 0; t < 8; ++t) acc[t] = (f32x4){0.f, 0.f, 0.f, 0.f};

    const int arow = r0 + (lane & 15);   // pad-row reads land in ws padding: safe
    const int kq = (lane >> 4) * 8;

    for (int s = 0; s < KS; ++s) {
        union { uint4 u; bf16x8 b; } af;
        af.u = *(const uint4*)(A + (long)arow * HID + s * 32 + kq);
#pragma unroll
        for (int t = 0; t < 8; ++t) {
            union { uint4 u; bf16x8 b; } bfr;
            bfr.u = *(const uint4*)(Wf + ((long)(t * KS + s) * 64 + lane) * 8);
            acc[t] = __builtin_amdgcn_mfma_f32_16x16x32_bf16(af.b, bfr.b, acc[t], 0, 0, 0);
        }
    }

    const int q = lane >> 4;
    float dv[4];
#pragma unroll
    for (int r = 0; r < 4; ++r) {
        int row = r0 + q * 4 + r;
        dv[r] = dinv[row < N_NODES ? row : 0];
    }
#pragma unroll
    for (int t = 0; t < 8; ++t) {
        int col = t * 16 + (lane & 15);
#pragma unroll
        for (int r = 0; r < 4; ++r) {
            int row = r0 + q * 4 + r;
            if (row < N_NODES)
                hp[(long)row * 128 + col] = f2bf(acc[t][r] * dv[r]);
        }
    }
}

// ---- K7: aggregate layer 2 — hp pre-scaled; 8 gathers in flight ----
__global__ __launch_bounds__(256) void aggregate4(const uint4* __restrict__ hp4,
                                                  const int* __restrict__ esrc,
                                                  const int* __restrict__ rowstart,
                                                  const int* __restrict__ cnt,
                                                  const float* __restrict__ dinv,
                                                  const float* __restrict__ bias,
                                                  uint4* __restrict__ hout4) {
    int node = blockIdx.x * 4 + (threadIdx.x >> 6);
    if (node >= N_NODES) return;
    int lane = threadIdx.x & 63;
    int eslot = lane >> 4;
    int ug = lane & 15;
    int start = rowstart[node];
    int end = start + cnt[node];

    float a[8];
#pragma unroll
    for (int k = 0; k < 8; ++k) a[k] = 0.f;

    for (int j = start; j < end; j += 32) {
        int e[8];
        uint4 v[8];
#pragma unroll
        for (int q = 0; q < 8; ++q) {
            e[q] = j + q * 4 + eslot;
            int s = esrc[min(e[q], end - 1)];
            v[q] = hp4[(long)s * 16 + ug];
        }
#pragma unroll
        for (int q = 0; q < 8; ++q) {
            if (e[q] < end) {
                a[0] += bflo(v[q].x); a[1] += bfhi(v[q].x);
                a[2] += bflo(v[q].y); a[3] += bfhi(v[q].y);
                a[4] += bflo(v[q].z); a[5] += bfhi(v[q].z);
                a[6] += bflo(v[q].w); a[7] += bfhi(v[q].w);
            }
        }
    }

#pragma unroll
    for (int k = 0; k < 8; ++k) {
        a[k] += __shfl_xor(a[k], 16);
        a[k] += __shfl_xor(a[k], 32);
    }

    if (eslot == 0) {
        uint4 vs = hp4[(long)node * 16 + ug];
        a[0] += bflo(vs.x); a[1] += bfhi(vs.x);
        a[2] += bflo(vs.y); a[3] += bfhi(vs.y);
        a[4] += bflo(vs.z); a[5] += bfhi(vs.z);
        a[6] += bflo(vs.w); a[7] += bfhi(vs.w);
        float d = dinv[node];
        float4 b0 = *(const float4*)(bias + ug * 8);
        float4 b1 = *(const float4*)(bias + ug * 8 + 4);
        float o0 = fmaxf(d * a[0] + b0.x, 0.f), o1 = fmaxf(d * a[1] + b0.y, 0.f);
        float o2 = fmaxf(d * a[2] + b0.z, 0.f), o3 = fmaxf(d * a[3] + b0.w, 0.f);
        float o4 = fmaxf(d * a[4] + b1.x, 0.f), o5 = fmaxf(d * a[5] + b1.y, 0.f);
        float o6 = fmaxf(d * a[6] + b1.z, 0.f), o7 = fmaxf(d * a[7] + b1.w, 0.f);
        uint4 o;
        o.x = (unsigned)f2bf(o0) | ((unsigned)f2bf(o1) << 16);
        o.y = (unsigned)f2bf(o2) | ((unsigned)f2bf(o3) << 16);
        o.z = (unsigned)f2bf(o4) | ((unsigned)f2bf(o5) << 16);
        o.w = (unsigned)f2bf(o6) | ((unsigned)f2bf(o7) << 16);
        hout4[(long)node * 16 + ug] = o;
    }
}

// ---- K8: pooling + head ----
__global__ __launch_bounds__(128) void pool_head(const unsigned short* __restrict__ h,
                                                 const int* __restrict__ batch,
                                                 const float* __restrict__ Wlin,
                                                 const float* __restrict__ blin,
                                                 float* __restrict__ out) {
    __shared__ int bnd[2];
    int g = blockIdx.x;
    int c = threadIdx.x;
    if (c < 2) {
        int target = g + c;
        int lo = 0, hi = N_NODES;
        while (lo < hi) {
            int mid = (lo + hi) >> 1;
            if (batch[mid] < target) lo = mid + 1;
            else hi = mid;
        }
        bnd[c] = lo;
    }
    __syncthreads();
    int s = bnd[0], e = bnd[1];

    float sum = 0.f;
    for (int i = s; i < e; ++i) {
        union { unsigned u; float f; } v;
        v.u = (unsigned)h[(long)i * 128 + c] << 16;
        sum += v.f;
    }
    float inv = (e > s) ? 1.0f / (float)(e - s) : 1.0f;
    float m = sum * inv;

    __shared__ float red[128][2];
    red[c][0] = m * Wlin[c * 2 + 0];
    red[c][1] = m * Wlin[c * 2 + 1];
    __syncthreads();
#pragma unroll
    for (int off = 64; off > 0; off >>= 1) {
        if (c < off) {
            red[c][0] += red[c + off][0];
            red[c][1] += red[c + off][1];
        }
        __syncthreads();
    }
    if (c < 2) out[g * 2 + c] = red[0][c] + blin[c];
}

extern "C" void kernel_launch(void* const* d_in, const int* in_sizes, int n_in,
                              void* d_out, int out_size, void* d_ws, size_t ws_size,
                              hipStream_t stream) {
    const float* x    = (const float*)d_in[0];
    const int*   ei   = (const int*)d_in[1];
    const int*   batch= (const int*)d_in[2];
    const float* W1   = (const float*)d_in[4];
    const float* b1   = (const float*)d_in[5];
    const float* W2   = (const float*)d_in[6];
    const float* b2   = (const float*)d_in[7];
    const float* Wlin = (const float*)d_in[8];
    const float* blin = (const float*)d_in[9];
    float* out = (float*)d_out;

    const int* src = ei;
    const int* dst = ei + N_EDGES;

    char* ws = (char*)d_ws;
    const size_t KB = 1024;
    const size_t MB = 1048576;

    float* dinv     = (float*)(ws);
    int*   cnt      = (int*)  (ws + 256 * KB);
    int*   rowstart = (int*)  (ws + 512 * KB);
    int*   total    = (int*)  (ws + 768 * KB);          // 196 ints
    int*   bh       = (int*)  (ws + 832 * KB);          // 98*196 ints
    int*   goff     = (int*)  (ws + 1 * MB);            // 98*196 ints
    uint2* ebuf     = (uint2*)(ws + 2 * MB);            // 6.4 MB
    int*   esrc     = (int*)  (ws + 9 * MB);            // 3.2 MB
    unsigned short* W2f = (unsigned short*)(ws + 12 * MB + 576 * KB);  // 32 KB
    unsigned short* hp  = (unsigned short*)(ws + 13 * MB);   // N_PAD x 128 bf16
    unsigned short* h   = (unsigned short*)(ws + 26 * MB);   // N_PAD x 128 bf16

    const int NB_AG = (N_NODES + 3) / 4;          // 12500

    // K1: gemm1-raw || chunk hists || W2 prep
    k1_fused<<<NB_G + NCH + 8, 256, 0, stream>>>(dst, W1, W2, W2f, bh, x, hp);
    // K2: per-bucket parallel scan
    goff_scan<<<NBUCK, 256, 0, stream>>>(bh, goff, total);
    // K3/K4: scatter + sort
    scatter_pairs<<<NCH, 256, 0, stream>>>(src, dst, goff, total, ebuf);
    bucket_sort<<<NBUCK, 256, 0, stream>>>(ebuf, total, rowstart, cnt, dinv, esrc);

    // K5: layer-1 aggregate (hp raw, dinv folded, 8-deep MLP)
    aggregate_w<<<NB_AG, 256, 0, stream>>>((const uint4*)hp, esrc, rowstart, cnt, dinv, b1, (uint4*)h);

    // K6/K7: layer 2
    gemm_mfma_bf16A<<<NB_G, 256, 0, stream>>>(h, W2f, dinv, hp);
    aggregate4<<<NB_AG, 256, 0, stream>>>((const uint4*)hp, esrc, rowstart, cnt, dinv, b2, (uint4*)h);

    // K8: pooling + head
    pool_head<<<N_GRAPHS, 128, 0, stream>>>(h, batch, Wlin, blin, out);
}

// Round 15
// 251.741 us; speedup vs baseline: 1.0044x; 1.0044x over previous
//
#include <hip/hip_runtime.h>

#define N_NODES 50000
#define N_PAD   50048   // 782 * 64
#define N_EDGES 800000
#define N_GRAPHS 512
#define F_IN 96
#define HID 128
#define NBUCK 196       // buckets of 256 nodes (dst >> 8)
#define CHUNK 8192      // edges per chunk block
#define NCH   98        // ceil(800000/8192)
#define NB_G 782        // gemm blocks (N_PAD/64)

typedef __bf16 bf16x8 __attribute__((ext_vector_type(8)));
typedef float  f32x4  __attribute__((ext_vector_type(4)));

__device__ __forceinline__ unsigned short f2bf(float f) {
    union { float f; unsigned u; } v; v.f = f;
    unsigned r = v.u + 0x7FFFu + ((v.u >> 16) & 1u);  // RNE
    return (unsigned short)(r >> 16);
}
__device__ __forceinline__ float bflo(unsigned u) {
    union { unsigned u; float f; } v; v.u = u << 16; return v.f;
}
__device__ __forceinline__ float bfhi(unsigned u) {
    union { unsigned u; float f; } v; v.u = u & 0xFFFF0000u; return v.f;
}

// build one B-fragment entry (8 bf16 = uint4) from f32 W[K x 128]
__device__ __forceinline__ uint4 frag_of(const float* __restrict__ W, int KS, int idx) {
    int t = idx / (KS * 64);
    int rem = idx % (KS * 64);
    int s = rem / 64;
    int l = rem & 63;
    int n = t * 16 + (l & 15);
    int k0 = s * 32 + (l >> 4) * 8;
    unsigned short v[8];
#pragma unroll
    for (int j = 0; j < 8; ++j) v[j] = f2bf(W[(long)(k0 + j) * 128 + n]);
    uint4 o;
    o.x = (unsigned)v[0] | ((unsigned)v[1] << 16);
    o.y = (unsigned)v[2] | ((unsigned)v[3] << 16);
    o.z = (unsigned)v[4] | ((unsigned)v[5] << 16);
    o.w = (unsigned)v[6] | ((unsigned)v[7] << 16);
    return o;
}

// ---- K1: gemm1-raw (0..781)  ||  chunk hists (782..879)  ||  W2 prep (880..887) ----
__global__ __launch_bounds__(256) void k1_fused(const int* __restrict__ dst,
                                                const float* __restrict__ W1,
                                                const float* __restrict__ W2,
                                                unsigned short* __restrict__ W2f,
                                                int* __restrict__ bh,
                                                const float* __restrict__ x,
                                                unsigned short* __restrict__ hp) {
    __shared__ uint4 w1lds[1536];  // 24 KB (aliased as hist for hist blocks)
    int blk = blockIdx.x;
    int tid = threadIdx.x;

    if (blk < NB_G) {
        for (int idx = tid; idx < 1536; idx += 256) w1lds[idx] = frag_of(W1, 3, idx);
        __syncthreads();

        const int KS = 3;
        const int wave = tid >> 6, lane = tid & 63;
        const int r0 = blk * 64 + wave * 16;
        f32x4 acc[8];
#pragma unroll
        for (int t = 0; t < 8; ++t) acc[t] = (f32x4){0.f, 0.f, 0.f, 0.f};
        int arow = r0 + (lane & 15);
        if (arow >= N_NODES) arow = N_NODES - 1;  // clamp; pad rows discarded on store
        const int kq = (lane >> 4) * 8;
        for (int s = 0; s < KS; ++s) {
            const float* ap = x + (long)arow * F_IN + s * 32 + kq;
            float4 a0 = *(const float4*)(ap);
            float4 a1 = *(const float4*)(ap + 4);
            union { uint4 u; bf16x8 b; } af;
            af.u.x = (unsigned)f2bf(a0.x) | ((unsigned)f2bf(a0.y) << 16);
            af.u.y = (unsigned)f2bf(a0.z) | ((unsigned)f2bf(a0.w) << 16);
            af.u.z = (unsigned)f2bf(a1.x) | ((unsigned)f2bf(a1.y) << 16);
            af.u.w = (unsigned)f2bf(a1.z) | ((unsigned)f2bf(a1.w) << 16);
#pragma unroll
            for (int t = 0; t < 8; ++t) {
                union { uint4 u; bf16x8 b; } bfr;
                bfr.u = w1lds[(t * KS + s) * 64 + lane];
                acc[t] = __builtin_amdgcn_mfma_f32_16x16x32_bf16(af.b, bfr.b, acc[t], 0, 0, 0);
            }
        }
        const int q = lane >> 4;
#pragma unroll
        for (int t = 0; t < 8; ++t) {
            int col = t * 16 + (lane & 15);
#pragma unroll
            for (int r = 0; r < 4; ++r) {
                int row = r0 + q * 4 + r;
                if (row < N_NODES) hp[(long)row * 128 + col] = f2bf(acc[t][r]);
            }
        }
    } else if (blk < NB_G + NCH) {
        int* bhist = (int*)w1lds;
        int c = blk - NB_G;
        for (int i = tid; i < NBUCK; i += 256) bhist[i] = 0;
        __syncthreads();
        int e0 = c * CHUNK, e1 = min(e0 + CHUNK, N_EDGES);
        int n4 = (e1 - e0) >> 2;  // chunk sizes divisible by 4
        const uint4* d4 = (const uint4*)(dst + e0);
        for (int i = tid; i < n4; i += 256) {
            uint4 d = d4[i];
            atomicAdd(&bhist[d.x >> 8], 1);
            atomicAdd(&bhist[d.y >> 8], 1);
            atomicAdd(&bhist[d.z >> 8], 1);
            atomicAdd(&bhist[d.w >> 8], 1);
        }
        __syncthreads();
        for (int i = tid; i < NBUCK; i += 256) bh[c * NBUCK + i] = bhist[i];
    } else {
        int idx = (blk - NB_G - NCH) * 256 + tid;  // 8 blocks x 256 = 2048 = 8*4*64
        *(uint4*)(W2f + (long)idx * 8) = frag_of(W2, 4, idx);
    }
}

// ---- K2: per-bucket scan over chunks (196 independent scans) ----
__global__ __launch_bounds__(256) void goff_scan(const int* __restrict__ bh,
                                                 int* __restrict__ goff,
                                                 int* __restrict__ total) {
    __shared__ int s[256];
    int b = blockIdx.x;
    int c = threadIdx.x;
    int v = (c < NCH) ? bh[c * NBUCK + b] : 0;
    s[c] = v;
    __syncthreads();
#pragma unroll
    for (int off = 1; off < 256; off <<= 1) {
        int t = 0;
        if (c >= off) t = s[c - off];
        __syncthreads();
        if (c >= off) s[c] += t;
        __syncthreads();
    }
    if (c < NCH) goff[c * NBUCK + b] = s[c] - v;  // exclusive (relative to bucket base)
    if (c == 255) total[b] = s[255];
}

// ---- K3: scatter pairs; bstart derived in-block from total[] ----
__global__ __launch_bounds__(256) void scatter_pairs(const int* __restrict__ src,
                                                     const int* __restrict__ dst,
                                                     const int* __restrict__ goff,
                                                     const int* __restrict__ total,
                                                     uint2* __restrict__ ebuf) {
    __shared__ int ts[256];
    __shared__ int lgoff[NBUCK];
    __shared__ int lcur[NBUCK];
    int tid = threadIdx.x;
    int c = blockIdx.x;
    int tv = (tid < NBUCK) ? total[tid] : 0;
    ts[tid] = tv;
    __syncthreads();
#pragma unroll
    for (int off = 1; off < 256; off <<= 1) {
        int t = 0;
        if (tid >= off) t = ts[tid - off];
        __syncthreads();
        if (tid >= off) ts[tid] += t;
        __syncthreads();
    }
    if (tid < NBUCK) {
        lgoff[tid] = goff[c * NBUCK + tid] + (ts[tid] - tv);  // + bstart[tid]
        lcur[tid] = 0;
    }
    __syncthreads();
    int e0 = c * CHUNK, e1 = min(e0 + CHUNK, N_EDGES);
    for (int e = e0 + tid; e < e1; e += 256) {
        int d = dst[e];
        int b = d >> 8;
        int slot = atomicAdd(&lcur[b], 1);
        ebuf[lgoff[b] + slot] = make_uint2((unsigned)src[e], (unsigned)d);
    }
}

// ---- K4: bucket sort; r0/r1 derived in-block from total[] ----
__global__ __launch_bounds__(256) void bucket_sort(const uint2* __restrict__ ebuf,
                                                   const int* __restrict__ total,
                                                   int* __restrict__ rowstart,
                                                   int* __restrict__ cnt,
                                                   float* __restrict__ dinv,
                                                   int* __restrict__ esrc) {
    __shared__ int ts[256];
    __shared__ int lcnt[256];
    __shared__ int ssc[256];
    __shared__ int ncur[256];
    int b = blockIdx.x, tid = threadIdx.x;
    int tv = (tid < NBUCK) ? total[tid] : 0;
    ts[tid] = tv;
    __syncthreads();
#pragma unroll
    for (int off = 1; off < 256; off <<= 1) {
        int t = 0;
        if (tid >= off) t = ts[tid - off];
        __syncthreads();
        if (tid >= off) ts[tid] += t;
        __syncthreads();
    }
    int r1 = ts[b];
    int r0 = r1 - total[b];
    int nbase = b * 256;
    lcnt[tid] = 0;
    __syncthreads();
    for (int i = r0 + tid; i < r1; i += 256)
        atomicAdd(&lcnt[(int)ebuf[i].y - nbase], 1);
    __syncthreads();
    int c = lcnt[tid];
    ssc[tid] = c;
    __syncthreads();
#pragma unroll
    for (int off = 1; off < 256; off <<= 1) {
        int t = 0;
        if (tid >= off) t = ssc[tid - off];
        __syncthreads();
        if (tid >= off) ssc[tid] += t;
        __syncthreads();
    }
    int rs = r0 + ssc[tid] - c;
    ncur[tid] = rs;
    int node = nbase + tid;
    if (node < N_NODES) {
        rowstart[node] = rs;
        cnt[node] = c;
        dinv[node] = rsqrtf((float)c + 1.0f);
    }
    __syncthreads();
    for (int i = r0 + tid; i < r1; i += 256) {
        uint2 p = ebuf[i];
        int pos = atomicAdd(&ncur[(int)p.y - nbase], 1);
        esrc[pos] = (int)p.x;
    }
}

// ---- K5: aggregate layer 1 — hp RAW; 4 gathers in flight (matched to mean degree 16) ----
__global__ __launch_bounds__(256) void aggregate_w(const uint4* __restrict__ hp4,
                                                   const int* __restrict__ esrc,
                                                   const int* __restrict__ rowstart,
                                                   const int* __restrict__ cnt,
                                                   const float* __restrict__ dinv,
                                                   const float* __restrict__ bias,
                                                   uint4* __restrict__ hout4) {
    int node = blockIdx.x * 4 + (threadIdx.x >> 6);
    if (node >= N_NODES) return;
    int lane = threadIdx.x & 63;
    int eslot = lane >> 4;
    int ug = lane & 15;
    int start = rowstart[node];
    int end = start + cnt[node];

    float a[8];
#pragma unroll
    for (int k = 0; k < 8; ++k) a[k] = 0.f;

    for (int j = start; j < end; j += 16) {
        int e[4];
        uint4 v[4];
        float w[4];
#pragma unroll
        for (int q = 0; q < 4; ++q) {
            e[q] = j + q * 4 + eslot;
            int s = esrc[min(e[q], end - 1)];
            v[q] = hp4[(long)s * 16 + ug];
            w[q] = dinv[s];
        }
#pragma unroll
        for (int q = 0; q < 4; ++q) {
            if (e[q] < end) {
                a[0] += w[q] * bflo(v[q].x); a[1] += w[q] * bfhi(v[q].x);
                a[2] += w[q] * bflo(v[q].y); a[3] += w[q] * bfhi(v[q].y);
                a[4] += w[q] * bflo(v[q].z); a[5] += w[q] * bfhi(v[q].z);
                a[6] += w[q] * bflo(v[q].w); a[7] += w[q] * bfhi(v[q].w);
            }
        }
    }

#pragma unroll
    for (int k = 0; k < 8; ++k) {
        a[k] += __shfl_xor(a[k], 16);
        a[k] += __shfl_xor(a[k], 32);
    }

    if (eslot == 0) {
        float d = dinv[node];
        uint4 vs = hp4[(long)node * 16 + ug];
        a[0] += d * bflo(vs.x); a[1] += d * bfhi(vs.x);
        a[2] += d * bflo(vs.y); a[3] += d * bfhi(vs.y);
        a[4] += d * bflo(vs.z); a[5] += d * bfhi(vs.z);
        a[6] += d * bflo(vs.w); a[7] += d * bfhi(vs.w);
        float4 b0 = *(const float4*)(bias + ug * 8);
        float4 b1 = *(const float4*)(bias + ug * 8 + 4);
        float o0 = fmaxf(d * a[0] + b0.x, 0.f), o1 = fmaxf(d * a[1] + b0.y, 0.f);
        float o2 = fmaxf(d * a[2] + b0.z, 0.f), o3 = fmaxf(d * a[3] + b0.w, 0.f);
        float o4 = fmaxf(d * a[4] + b1.x, 0.f), o5 = fmaxf(d * a[5] + b1.y, 0.f);
        float o6 = fmaxf(d * a[6] + b1.z, 0.f), o7 = fmaxf(d * a[7] + b1.w, 0.f);
        uint4 o;
        o.x = (unsigned)f2bf(o0) | ((unsigned)f2bf(o1) << 16);
        o.y = (unsigned)f2bf(o2) | ((unsigned)f2bf(o3) << 16);
        o.z = (unsigned)f2bf(o4) | ((unsigned)f2bf(o5) << 16);
        o.w = (unsigned)f2bf(o6) | ((unsigned)f2bf(o7) << 16);
        hout4[(long)node * 16 + ug] = o;
    }
}

// ---- K6: gemm layer 2: hp = bf16(dinv * (h @ W2)) ----
__global__ __launch_bounds__(256) void gemm_mfma_bf16A(const unsigned short* __restrict__ A,
                                                       const unsigned short* __restrict__ Wf,
                                                       const float* __restrict__ dinv,
                                                       unsigned short* __restrict__ hp) {
    const int KS = 4;
    const int wave = threadIdx.x >> 6;
    const int lane = threadIdx.x & 63;
    const int r0 = blockIdx.x * 64 + wave * 16;

    f32x4 acc[8];
#pragma unroll
    for (int t = 0; t < 8; ++t) acc[t] = (f32x4){0.f, 0.f, 0.f, 0.f};

    const int arow = r0 + (lane & 15);   // pad-row reads land in ws padding: safe
    const int kq = (lane >> 4) * 8;

    for (int s = 0; s < KS; ++s) {
        union { uint4 u; bf16x8 b; } af;
        af.u = *(const uint4*)(A + (long)arow * HID + s * 32 + kq);
#pragma unroll
        for (int t = 0; t < 8; ++t) {
            union { uint4 u; bf16x8 b; } bfr;
            bfr.u = *(const uint4*)(Wf + ((long)(t * KS + s) * 64 + lane) * 8);
            acc[t] = __builtin_amdgcn_mfma_f32_16x16x32_bf16(af.b, bfr.b, acc[t], 0, 0, 0);
        }
    }

    const int q = lane >> 4;
    float dv[4];
#pragma unroll
    for (int r = 0; r < 4; ++r) {
        int row = r0 + q * 4 + r;
        dv[r] = dinv[row < N_NODES ? row : 0];
    }
#pragma unroll
    for (int t = 0; t < 8; ++t) {
        int col = t * 16 + (lane & 15);
#pragma unroll
        for (int r = 0; r < 4; ++r) {
            int row = r0 + q * 4 + r;
            if (row < N_NODES)
                hp[(long)row * 128 + col] = f2bf(acc[t][r] * dv[r]);
        }
    }
}

// ---- K7: aggregate layer 2 — hp pre-scaled; 4 gathers in flight ----
__global__ __launch_bounds__(256) void aggregate4(const uint4* __restrict__ hp4,
                                                  const int* __restrict__ esrc,
                                                  const int* __restrict__ rowstart,
                                                  const int* __restrict__ cnt,
                                                  const float* __restrict__ dinv,
                                                  const float* __restrict__ bias,
                                                  uint4* __restrict__ hout4) {
    int node = blockIdx.x * 4 + (threadIdx.x >> 6);
    if (node >= N_NODES) return;
    int lane = threadIdx.x & 63;
    int eslot = lane >> 4;
    int ug = lane & 15;
    int start = rowstart[node];
    int end = start + cnt[node];

    float a[8];
#pragma unroll
    for (int k = 0; k < 8; ++k) a[k] = 0.f;

    for (int j = start; j < end; j += 16) {
        int e[4];
        uint4 v[4];
#pragma unroll
        for (int q = 0; q < 4; ++q) {
            e[q] = j + q * 4 + eslot;
            int s = esrc[min(e[q], end - 1)];
            v[q] = hp4[(long)s * 16 + ug];
        }
#pragma unroll
        for (int q = 0; q < 4; ++q) {
            if (e[q] < end) {
                a[0] += bflo(v[q].x); a[1] += bfhi(v[q].x);
                a[2] += bflo(v[q].y); a[3] += bfhi(v[q].y);
                a[4] += bflo(v[q].z); a[5] += bfhi(v[q].z);
                a[6] += bflo(v[q].w); a[7] += bfhi(v[q].w);
            }
        }
    }

#pragma unroll
    for (int k = 0; k < 8; ++k) {
        a[k] += __shfl_xor(a[k], 16);
        a[k] += __shfl_xor(a[k], 32);
    }

    if (eslot == 0) {
        uint4 vs = hp4[(long)node * 16 + ug];
        a[0] += bflo(vs.x); a[1] += bfhi(vs.x);
        a[2] += bflo(vs.y); a[3] += bfhi(vs.y);
        a[4] += bflo(vs.z); a[5] += bfhi(vs.z);
        a[6] += bflo(vs.w); a[7] += bfhi(vs.w);
        float d = dinv[node];
        float4 b0 = *(const float4*)(bias + ug * 8);
        float4 b1 = *(const float4*)(bias + ug * 8 + 4);
        float o0 = fmaxf(d * a[0] + b0.x, 0.f), o1 = fmaxf(d * a[1] + b0.y, 0.f);
        float o2 = fmaxf(d * a[2] + b0.z, 0.f), o3 = fmaxf(d * a[3] + b0.w, 0.f);
        float o4 = fmaxf(d * a[4] + b1.x, 0.f), o5 = fmaxf(d * a[5] + b1.y, 0.f);
        float o6 = fmaxf(d * a[6] + b1.z, 0.f), o7 = fmaxf(d * a[7] + b1.w, 0.f);
        uint4 o;
        o.x = (unsigned)f2bf(o0) | ((unsigned)f2bf(o1) << 16);
        o.y = (unsigned)f2bf(o2) | ((unsigned)f2bf(o3) << 16);
        o.z = (unsigned)f2bf(o4) | ((unsigned)f2bf(o5) << 16);
        o.w = (unsigned)f2bf(o6) | ((unsigned)f2bf(o7) << 16);
        hout4[(long)node * 16 + ug] = o;
    }
}

// ---- K8: pooling + head ----
__global__ __launch_bounds__(128) void pool_head(const unsigned short* __restrict__ h,
                                                 const int* __restrict__ batch,
                                                 const float* __restrict__ Wlin,
                                                 const float* __restrict__ blin,
                                                 float* __restrict__ out) {
    __shared__ int bnd[2];
    int g = blockIdx.x;
    int c = threadIdx.x;
    if (c < 2) {
        int target = g + c;
        int lo = 0, hi = N_NODES;
        while (lo < hi) {
            int mid = (lo + hi) >> 1;
            if (batch[mid] < target) lo = mid + 1;
            else hi = mid;
        }
        bnd[c] = lo;
    }
    __syncthreads();
    int s = bnd[0], e = bnd[1];

    float sum = 0.f;
    for (int i = s; i < e; ++i) {
        union { unsigned u; float f; } v;
        v.u = (unsigned)h[(long)i * 128 + c] << 16;
        sum += v.f;
    }
    float inv = (e > s) ? 1.0f / (float)(e - s) : 1.0f;
    float m = sum * inv;

    __shared__ float red[128][2];
    red[c][0] = m * Wlin[c * 2 + 0];
    red[c][1] = m * Wlin[c * 2 + 1];
    __syncthreads();
#pragma unroll
    for (int off = 64; off > 0; off >>= 1) {
        if (c < off) {
            red[c][0] += red[c + off][0];
            red[c][1] += red[c + off][1];
        }
        __syncthreads();
    }
    if (c < 2) out[g * 2 + c] = red[0][c] + blin[c];
}

extern "C" void kernel_launch(void* const* d_in, const int* in_sizes, int n_in,
                              void* d_out, int out_size, void* d_ws, size_t ws_size,
                              hipStream_t stream) {
    const float* x    = (const float*)d_in[0];
    const int*   ei   = (const int*)d_in[1];
    const int*   batch= (const int*)d_in[2];
    const float* W1   = (const float*)d_in[4];
    const float* b1   = (const float*)d_in[5];
    const float* W2   = (const float*)d_in[6];
    const float* b2   = (const float*)d_in[7];
    const float* Wlin = (const float*)d_in[8];
    const float* blin = (const float*)d_in[9];
    float* out = (float*)d_out;

    const int* src = ei;
    const int* dst = ei + N_EDGES;

    char* ws = (char*)d_ws;
    const size_t KB = 1024;
    const size_t MB = 1048576;

    float* dinv     = (float*)(ws);
    int*   cnt      = (int*)  (ws + 256 * KB);
    int*   rowstart = (int*)  (ws + 512 * KB);
    int*   total    = (int*)  (ws + 768 * KB);          // 196 ints
    int*   bh       = (int*)  (ws + 832 * KB);          // 98*196 ints
    int*   goff     = (int*)  (ws + 1 * MB);            // 98*196 ints
    uint2* ebuf     = (uint2*)(ws + 2 * MB);            // 6.4 MB
    int*   esrc     = (int*)  (ws + 9 * MB);            // 3.2 MB
    unsigned short* W2f = (unsigned short*)(ws + 12 * MB + 576 * KB);  // 32 KB
    unsigned short* hp  = (unsigned short*)(ws + 13 * MB);   // N_PAD x 128 bf16
    unsigned short* h   = (unsigned short*)(ws + 26 * MB);   // N_PAD x 128 bf16

    const int NB_AG = (N_NODES + 3) / 4;          // 12500

    // K1: gemm1-raw || chunk hists || W2 prep
    k1_fused<<<NB_G + NCH + 8, 256, 0, stream>>>(dst, W1, W2, W2f, bh, x, hp);
    // K2: per-bucket parallel scan
    goff_scan<<<NBUCK, 256, 0, stream>>>(bh, goff, total);
    // K3/K4: scatter + sort
    scatter_pairs<<<NCH, 256, 0, stream>>>(src, dst, goff, total, ebuf);
    bucket_sort<<<NBUCK, 256, 0, stream>>>(ebuf, total, rowstart, cnt, dinv, esrc);

    // K5: layer-1 aggregate (hp raw, dinv folded, 4-deep MLP)
    aggregate_w<<<NB_AG, 256, 0, stream>>>((const uint4*)hp, esrc, rowstart, cnt, dinv, b1, (uint4*)h);

    // K6/K7: layer 2
    gemm_mfma_bf16A<<<NB_G, 256, 0, stream>>>(h, W2f, dinv, hp);
    aggregate4<<<NB_AG, 256, 0, stream>>>((const uint4*)hp, esrc, rowstart, cnt, dinv, b2, (uint4*)h);

    // K8: pooling + head
    pool_head<<<N_GRAPHS, 128, 0, stream>>>(h, batch, Wlin, blin, out);
}

// Round 16
// 241.620 us; speedup vs baseline: 1.0465x; 1.0419x over previous
//
#include <hip/hip_runtime.h>

#define N_NODES 50000
#define N_PAD   50048   // 782 * 64
#define N_EDGES 800000
#define N_GRAPHS 512
#define F_IN 96
#define HID 128
#define NBUCK 196       // buckets of 256 nodes (dst >> 8)
#define CHUNK 4096      // edges per chunk block
#define NCH   196       // ceil(800000/4096)
#define NB_G 782        // gemm blocks (N_PAD/64)

typedef __bf16 bf16x8 __attribute__((ext_vector_type(8)));
typedef float  f32x4  __attribute__((ext_vector_type(4)));

__device__ __forceinline__ unsigned short f2bf(float f) {
    union { float f; unsigned u; } v; v.f = f;
    unsigned r = v.u + 0x7FFFu + ((v.u >> 16) & 1u);  // RNE
    return (unsigned short)(r >> 16);
}
__device__ __forceinline__ float bflo(unsigned u) {
    union { unsigned u; float f; } v; v.u = u << 16; return v.f;
}
__device__ __forceinline__ float bfhi(unsigned u) {
    union { unsigned u; float f; } v; v.u = u & 0xFFFF0000u; return v.f;
}

// build one B-fragment entry (8 bf16 = uint4) from f32 W[K x 128]
__device__ __forceinline__ uint4 frag_of(const float* __restrict__ W, int KS, int idx) {
    int t = idx / (KS * 64);
    int rem = idx % (KS * 64);
    int s = rem / 64;
    int l = rem & 63;
    int n = t * 16 + (l & 15);
    int k0 = s * 32 + (l >> 4) * 8;
    unsigned short v[8];
#pragma unroll
    for (int j = 0; j < 8; ++j) v[j] = f2bf(W[(long)(k0 + j) * 128 + n]);
    uint4 o;
    o.x = (unsigned)v[0] | ((unsigned)v[1] << 16);
    o.y = (unsigned)v[2] | ((unsigned)v[3] << 16);
    o.z = (unsigned)v[4] | ((unsigned)v[5] << 16);
    o.w = (unsigned)v[6] | ((unsigned)v[7] << 16);
    return o;
}

// ---- K1: gemm1-raw (0..781)  ||  chunk hists (782..977)  ||  W2 prep (978..985) ----
__global__ __launch_bounds__(256) void k1_fused(const int* __restrict__ dst,
                                                const float* __restrict__ W1,
                                                const float* __restrict__ W2,
                                                unsigned short* __restrict__ W2f,
                                                int* __restrict__ bh,
                                                const float* __restrict__ x,
                                                unsigned short* __restrict__ hp) {
    __shared__ uint4 w1lds[1536];  // 24 KB (aliased as hist for hist blocks)
    int blk = blockIdx.x;
    int tid = threadIdx.x;

    if (blk < NB_G) {
        for (int idx = tid; idx < 1536; idx += 256) w1lds[idx] = frag_of(W1, 3, idx);
        __syncthreads();

        const int KS = 3;
        const int wave = tid >> 6, lane = tid & 63;
        const int r0 = blk * 64 + wave * 16;
        f32x4 acc[8];
#pragma unroll
        for (int t = 0; t < 8; ++t) acc[t] = (f32x4){0.f, 0.f, 0.f, 0.f};
        int arow = r0 + (lane & 15);
        if (arow >= N_NODES) arow = N_NODES - 1;  // clamp; pad rows discarded on store
        const int kq = (lane >> 4) * 8;
        for (int s = 0; s < KS; ++s) {
            const float* ap = x + (long)arow * F_IN + s * 32 + kq;
            float4 a0 = *(const float4*)(ap);
            float4 a1 = *(const float4*)(ap + 4);
            union { uint4 u; bf16x8 b; } af;
            af.u.x = (unsigned)f2bf(a0.x) | ((unsigned)f2bf(a0.y) << 16);
            af.u.y = (unsigned)f2bf(a0.z) | ((unsigned)f2bf(a0.w) << 16);
            af.u.z = (unsigned)f2bf(a1.x) | ((unsigned)f2bf(a1.y) << 16);
            af.u.w = (unsigned)f2bf(a1.z) | ((unsigned)f2bf(a1.w) << 16);
#pragma unroll
            for (int t = 0; t < 8; ++t) {
                union { uint4 u; bf16x8 b; } bfr;
                bfr.u = w1lds[(t * KS + s) * 64 + lane];
                acc[t] = __builtin_amdgcn_mfma_f32_16x16x32_bf16(af.b, bfr.b, acc[t], 0, 0, 0);
            }
        }
        const int q = lane >> 4;
#pragma unroll
        for (int t = 0; t < 8; ++t) {
            int col = t * 16 + (lane & 15);
#pragma unroll
            for (int r = 0; r < 4; ++r) {
                int row = r0 + q * 4 + r;
                if (row < N_NODES) hp[(long)row * 128 + col] = f2bf(acc[t][r]);
            }
        }
    } else if (blk < NB_G + NCH) {
        int* bhist = (int*)w1lds;
        int c = blk - NB_G;
        for (int i = tid; i < NBUCK; i += 256) bhist[i] = 0;
        __syncthreads();
        int e0 = c * CHUNK, e1 = min(e0 + CHUNK, N_EDGES);
        int n4 = (e1 - e0) >> 2;  // chunk sizes divisible by 4
        const uint4* d4 = (const uint4*)(dst + e0);
        for (int i = tid; i < n4; i += 256) {
            uint4 d = d4[i];
            atomicAdd(&bhist[d.x >> 8], 1);
            atomicAdd(&bhist[d.y >> 8], 1);
            atomicAdd(&bhist[d.z >> 8], 1);
            atomicAdd(&bhist[d.w >> 8], 1);
        }
        __syncthreads();
        for (int i = tid; i < NBUCK; i += 256) bh[c * NBUCK + i] = bhist[i];
    } else {
        int idx = (blk - NB_G - NCH) * 256 + tid;  // 8 blocks x 256 = 2048 = 8*4*64
        *(uint4*)(W2f + (long)idx * 8) = frag_of(W2, 4, idx);
    }
}

// ---- K2: per-bucket scan over chunks (196 independent scans) ----
__global__ __launch_bounds__(256) void goff_scan(const int* __restrict__ bh,
                                                 int* __restrict__ goff,
                                                 int* __restrict__ total) {
    __shared__ int s[256];
    int b = blockIdx.x;
    int c = threadIdx.x;
    int v = (c < NCH) ? bh[c * NBUCK + b] : 0;
    s[c] = v;
    __syncthreads();
#pragma unroll
    for (int off = 1; off < 256; off <<= 1) {
        int t = 0;
        if (c >= off) t = s[c - off];
        __syncthreads();
        if (c >= off) s[c] += t;
        __syncthreads();
    }
    if (c < NCH) goff[c * NBUCK + b] = s[c] - v;  // exclusive (relative to bucket base)
    if (c == 255) total[b] = s[255];
}

// ---- K3: scatter pairs (PACKED: src in [0:16), local-dst in [16:24)) ----
__global__ __launch_bounds__(256) void scatter_pairs(const int* __restrict__ src,
                                                     const int* __restrict__ dst,
                                                     const int* __restrict__ goff,
                                                     const int* __restrict__ total,
                                                     unsigned* __restrict__ ebuf) {
    __shared__ int ts[256];
    __shared__ int lgoff[NBUCK];
    __shared__ int lcur[NBUCK];
    int tid = threadIdx.x;
    int c = blockIdx.x;
    int tv = (tid < NBUCK) ? total[tid] : 0;
    ts[tid] = tv;
    __syncthreads();
#pragma unroll
    for (int off = 1; off < 256; off <<= 1) {
        int t = 0;
        if (tid >= off) t = ts[tid - off];
        __syncthreads();
        if (tid >= off) ts[tid] += t;
        __syncthreads();
    }
    if (tid < NBUCK) {
        lgoff[tid] = goff[c * NBUCK + tid] + (ts[tid] - tv);  // + bstart[tid]
        lcur[tid] = 0;
    }
    __syncthreads();
    int e0 = c * CHUNK, e1 = min(e0 + CHUNK, N_EDGES);
    for (int e = e0 + tid; e < e1; e += 256) {
        int d = dst[e];
        int b = d >> 8;
        int slot = atomicAdd(&lcur[b], 1);
        // src < 50000 < 2^16; local dst = d & 255 in bits [16:24)
        ebuf[lgoff[b] + slot] = (unsigned)src[e] | ((unsigned)(d & 255) << 16);
    }
}

// ---- K4: bucket sort; unpack 32-bit entries ----
__global__ __launch_bounds__(256) void bucket_sort(const unsigned* __restrict__ ebuf,
                                                   const int* __restrict__ total,
                                                   int* __restrict__ rowstart,
                                                   int* __restrict__ cnt,
                                                   float* __restrict__ dinv,
                                                   int* __restrict__ esrc) {
    __shared__ int ts[256];
    __shared__ int lcnt[256];
    __shared__ int ssc[256];
    __shared__ int ncur[256];
    int b = blockIdx.x, tid = threadIdx.x;
    int tv = (tid < NBUCK) ? total[tid] : 0;
    ts[tid] = tv;
    __syncthreads();
#pragma unroll
    for (int off = 1; off < 256; off <<= 1) {
        int t = 0;
        if (tid >= off) t = ts[tid - off];
        __syncthreads();
        if (tid >= off) ts[tid] += t;
        __syncthreads();
    }
    int r1 = ts[b];
    int r0 = r1 - total[b];
    int nbase = b * 256;
    lcnt[tid] = 0;
    __syncthreads();
    for (int i = r0 + tid; i < r1; i += 256)
        atomicAdd(&lcnt[ebuf[i] >> 16], 1);
    __syncthreads();
    int c = lcnt[tid];
    ssc[tid] = c;
    __syncthreads();
#pragma unroll
    for (int off = 1; off < 256; off <<= 1) {
        int t = 0;
        if (tid >= off) t = ssc[tid - off];
        __syncthreads();
        if (tid >= off) ssc[tid] += t;
        __syncthreads();
    }
    int rs = r0 + ssc[tid] - c;
    ncur[tid] = rs;
    int node = nbase + tid;
    if (node < N_NODES) {
        rowstart[node] = rs;
        cnt[node] = c;
        dinv[node] = rsqrtf((float)c + 1.0f);
    }
    __syncthreads();
    for (int i = r0 + tid; i < r1; i += 256) {
        unsigned p = ebuf[i];
        int pos = atomicAdd(&ncur[p >> 16], 1);
        esrc[pos] = (int)(p & 0xFFFFu);
    }
}

// ---- K5: aggregate layer 1 — hp RAW; 4 gathers in flight; dinv folded ----
__global__ __launch_bounds__(256) void aggregate_w(const uint4* __restrict__ hp4,
                                                   const int* __restrict__ esrc,
                                                   const int* __restrict__ rowstart,
                                                   const int* __restrict__ cnt,
                                                   const float* __restrict__ dinv,
                                                   const float* __restrict__ bias,
                                                   uint4* __restrict__ hout4) {
    int node = blockIdx.x * 4 + (threadIdx.x >> 6);
    if (node >= N_NODES) return;
    int lane = threadIdx.x & 63;
    int eslot = lane >> 4;
    int ug = lane & 15;
    int start = rowstart[node];
    int end = start + cnt[node];

    float a[8];
#pragma unroll
    for (int k = 0; k < 8; ++k) a[k] = 0.f;

    for (int j = start; j < end; j += 16) {
        int e[4];
        uint4 v[4];
        float w[4];
#pragma unroll
        for (int q = 0; q < 4; ++q) {
            e[q] = j + q * 4 + eslot;
            int s = esrc[min(e[q], end - 1)];
            v[q] = hp4[(long)s * 16 + ug];
            w[q] = dinv[s];
        }
#pragma unroll
        for (int q = 0; q < 4; ++q) {
            if (e[q] < end) {
                a[0] += w[q] * bflo(v[q].x); a[1] += w[q] * bfhi(v[q].x);
                a[2] += w[q] * bflo(v[q].y); a[3] += w[q] * bfhi(v[q].y);
                a[4] += w[q] * bflo(v[q].z); a[5] += w[q] * bfhi(v[q].z);
                a[6] += w[q] * bflo(v[q].w); a[7] += w[q] * bfhi(v[q].w);
            }
        }
    }

#pragma unroll
    for (int k = 0; k < 8; ++k) {
        a[k] += __shfl_xor(a[k], 16);
        a[k] += __shfl_xor(a[k], 32);
    }

    if (eslot == 0) {
        float d = dinv[node];
        uint4 vs = hp4[(long)node * 16 + ug];
        a[0] += d * bflo(vs.x); a[1] += d * bfhi(vs.x);
        a[2] += d * bflo(vs.y); a[3] += d * bfhi(vs.y);
        a[4] += d * bflo(vs.z); a[5] += d * bfhi(vs.z);
        a[6] += d * bflo(vs.w); a[7] += d * bfhi(vs.w);
        float4 b0 = *(const float4*)(bias + ug * 8);
        float4 b1 = *(const float4*)(bias + ug * 8 + 4);
        float o0 = fmaxf(d * a[0] + b0.x, 0.f), o1 = fmaxf(d * a[1] + b0.y, 0.f);
        float o2 = fmaxf(d * a[2] + b0.z, 0.f), o3 = fmaxf(d * a[3] + b0.w, 0.f);
        float o4 = fmaxf(d * a[4] + b1.x, 0.f), o5 = fmaxf(d * a[5] + b1.y, 0.f);
        float o6 = fmaxf(d * a[6] + b1.z, 0.f), o7 = fmaxf(d * a[7] + b1.w, 0.f);
        uint4 o;
        o.x = (unsigned)f2bf(o0) | ((unsigned)f2bf(o1) << 16);
        o.y = (unsigned)f2bf(o2) | ((unsigned)f2bf(o3) << 16);
        o.z = (unsigned)f2bf(o4) | ((unsigned)f2bf(o5) << 16);
        o.w = (unsigned)f2bf(o6) | ((unsigned)f2bf(o7) << 16);
        hout4[(long)node * 16 + ug] = o;
    }
}

// ---- K6: gemm layer 2: hp = bf16(dinv * (h @ W2)) ----
__global__ __launch_bounds__(256) void gemm_mfma_bf16A(const unsigned short* __restrict__ A,
                                                       const unsigned short* __restrict__ Wf,
                                                       const float* __restrict__ dinv,
                                                       unsigned short* __restrict__ hp) {
    const int KS = 4;
    const int wave = threadIdx.x >> 6;
    const int lane = threadIdx.x & 63;
    const int r0 = blockIdx.x * 64 + wave * 16;

    f32x4 acc[8];
#pragma unroll
    for (int t = 0; t < 8; ++t) acc[t] = (f32x4){0.f, 0.f, 0.f, 0.f};

    const int arow = r0 + (lane & 15);   // pad-row reads land in ws padding: safe
    const int kq = (lane >> 4) * 8;

    for (int s = 0; s < KS; ++s) {
        union { uint4 u; bf16x8 b; } af;
        af.u = *(const uint4*)(A + (long)arow * HID + s * 32 + kq);
#pragma unroll
        for (int t = 0; t < 8; ++t) {
            union { uint4 u; bf16x8 b; } bfr;
            bfr.u = *(const uint4*)(Wf + ((long)(t * KS + s) * 64 + lane) * 8);
            acc[t] = __builtin_amdgcn_mfma_f32_16x16x32_bf16(af.b, bfr.b, acc[t], 0, 0, 0);
        }
    }

    const int q = lane >> 4;
    float dv[4];
#pragma unroll
    for (int r = 0; r < 4; ++r) {
        int row = r0 + q * 4 + r;
        dv[r] = dinv[row < N_NODES ? row : 0];
    }
#pragma unroll
    for (int t = 0; t < 8; ++t) {
        int col = t * 16 + (lane & 15);
#pragma unroll
        for (int r = 0; r < 4; ++r) {
            int row = r0 + q * 4 + r;
            if (row < N_NODES)
                hp[(long)row * 128 + col] = f2bf(acc[t][r] * dv[r]);
        }
    }
}

// ---- K7: aggregate layer 2 — hp pre-scaled; 4 gathers in flight ----
__global__ __launch_bounds__(256) void aggregate4(const uint4* __restrict__ hp4,
                                                  const int* __restrict__ esrc,
                                                  const int* __restrict__ rowstart,
                                                  const int* __restrict__ cnt,
                                                  const float* __restrict__ dinv,
                                                  const float* __restrict__ bias,
                                                  uint4* __restrict__ hout4) {
    int node = blockIdx.x * 4 + (threadIdx.x >> 6);
    if (node >= N_NODES) return;
    int lane = threadIdx.x & 63;
    int eslot = lane >> 4;
    int ug = lane & 15;
    int start = rowstart[node];
    int end = start + cnt[node];

    float a[8];
#pragma unroll
    for (int k = 0; k < 8; ++k) a[k] = 0.f;

    for (int j = start; j < end; j += 16) {
        int e[4];
        uint4 v[4];
#pragma unroll
        for (int q = 0; q < 4; ++q) {
            e[q] = j + q * 4 + eslot;
            int s = esrc[min(e[q], end - 1)];
            v[q] = hp4[(long)s * 16 + ug];
        }
#pragma unroll
        for (int q = 0; q < 4; ++q) {
            if (e[q] < end) {
                a[0] += bflo(v[q].x); a[1] += bfhi(v[q].x);
                a[2] += bflo(v[q].y); a[3] += bfhi(v[q].y);
                a[4] += bflo(v[q].z); a[5] += bfhi(v[q].z);
                a[6] += bflo(v[q].w); a[7] += bfhi(v[q].w);
            }
        }
    }

#pragma unroll
    for (int k = 0; k < 8; ++k) {
        a[k] += __shfl_xor(a[k], 16);
        a[k] += __shfl_xor(a[k], 32);
    }

    if (eslot == 0) {
        uint4 vs = hp4[(long)node * 16 + ug];
        a[0] += bflo(vs.x); a[1] += bfhi(vs.x);
        a[2] += bflo(vs.y); a[3] += bfhi(vs.y);
        a[4] += bflo(vs.z); a[5] += bfhi(vs.z);
        a[6] += bflo(vs.w); a[7] += bfhi(vs.w);
        float d = dinv[node];
        float4 b0 = *(const float4*)(bias + ug * 8);
        float4 b1 = *(const float4*)(bias + ug * 8 + 4);
        float o0 = fmaxf(d * a[0] + b0.x, 0.f), o1 = fmaxf(d * a[1] + b0.y, 0.f);
        float o2 = fmaxf(d * a[2] + b0.z, 0.f), o3 = fmaxf(d * a[3] + b0.w, 0.f);
        float o4 = fmaxf(d * a[4] + b1.x, 0.f), o5 = fmaxf(d * a[5] + b1.y, 0.f);
        float o6 = fmaxf(d * a[6] + b1.z, 0.f), o7 = fmaxf(d * a[7] + b1.w, 0.f);
        uint4 o;
        o.x = (unsigned)f2bf(o0) | ((unsigned)f2bf(o1) << 16);
        o.y = (unsigned)f2bf(o2) | ((unsigned)f2bf(o3) << 16);
        o.z = (unsigned)f2bf(o4) | ((unsigned)f2bf(o5) << 16);
        o.w = (unsigned)f2bf(o6) | ((unsigned)f2bf(o7) << 16);
        hout4[(long)node * 16 + ug] = o;
    }
}

// ---- K8: pooling + head ----
__global__ __launch_bounds__(128) void pool_head(const unsigned short* __restrict__ h,
                                                 const int* __restrict__ batch,
                                                 const float* __restrict__ Wlin,
                                                 const float* __restrict__ blin,
                                                 float* __restrict__ out) {
    __shared__ int bnd[2];
    int g = blockIdx.x;
    int c = threadIdx.x;
    if (c < 2) {
        int target = g + c;
        int lo = 0, hi = N_NODES;
        while (lo < hi) {
            int mid = (lo + hi) >> 1;
            if (batch[mid] < target) lo = mid + 1;
            else hi = mid;
        }
        bnd[c] = lo;
    }
    __syncthreads();
    int s = bnd[0], e = bnd[1];

    float sum = 0.f;
    for (int i = s; i < e; ++i) {
        union { unsigned u; float f; } v;
        v.u = (unsigned)h[(long)i * 128 + c] << 16;
        sum += v.f;
    }
    float inv = (e > s) ? 1.0f / (float)(e - s) : 1.0f;
    float m = sum * inv;

    __shared__ float red[128][2];
    red[c][0] = m * Wlin[c * 2 + 0];
    red[c][1] = m * Wlin[c * 2 + 1];
    __syncthreads();
#pragma unroll
    for (int off = 64; off > 0; off >>= 1) {
        if (c < off) {
            red[c][0] += red[c + off][0];
            red[c][1] += red[c + off][1];
        }
        __syncthreads();
    }
    if (c < 2) out[g * 2 + c] = red[0][c] + blin[c];
}

extern "C" void kernel_launch(void* const* d_in, const int* in_sizes, int n_in,
                              void* d_out, int out_size, void* d_ws, size_t ws_size,
                              hipStream_t stream) {
    const float* x    = (const float*)d_in[0];
    const int*   ei   = (const int*)d_in[1];
    const int*   batch= (const int*)d_in[2];
    const float* W1   = (const float*)d_in[4];
    const float* b1   = (const float*)d_in[5];
    const float* W2   = (const float*)d_in[6];
    const float* b2   = (const float*)d_in[7];
    const float* Wlin = (const float*)d_in[8];
    const float* blin = (const float*)d_in[9];
    float* out = (float*)d_out;

    const int* src = ei;
    const int* dst = ei + N_EDGES;

    char* ws = (char*)d_ws;
    const size_t KB = 1024;
    const size_t MB = 1048576;

    float*    dinv     = (float*)(ws);
    int*      cnt      = (int*)  (ws + 256 * KB);
    int*      rowstart = (int*)  (ws + 512 * KB);
    int*      total    = (int*)  (ws + 768 * KB);          // 196 ints
    int*      bh       = (int*)  (ws + 832 * KB);          // 196*196 ints
    int*      goff     = (int*)  (ws + 1 * MB);            // 196*196 ints
    unsigned* ebuf     = (unsigned*)(ws + 2 * MB);         // 3.2 MB (packed)
    int*      esrc     = (int*)  (ws + 9 * MB);            // 3.2 MB
    unsigned short* W2f = (unsigned short*)(ws + 12 * MB + 576 * KB);  // 32 KB
    unsigned short* hp  = (unsigned short*)(ws + 13 * MB);   // N_PAD x 128 bf16
    unsigned short* h   = (unsigned short*)(ws + 26 * MB);   // N_PAD x 128 bf16

    const int NB_AG = (N_NODES + 3) / 4;          // 12500

    // K1: gemm1-raw || chunk hists || W2 prep
    k1_fused<<<NB_G + NCH + 8, 256, 0, stream>>>(dst, W1, W2, W2f, bh, x, hp);
    // K2: per-bucket parallel scan
    goff_scan<<<NBUCK, 256, 0, stream>>>(bh, goff, total);
    // K3/K4: scatter (packed 32-bit) + sort
    scatter_pairs<<<NCH, 256, 0, stream>>>(src, dst, goff, total, ebuf);
    bucket_sort<<<NBUCK, 256, 0, stream>>>(ebuf, total, rowstart, cnt, dinv, esrc);

    // K5: layer-1 aggregate (hp raw, dinv folded, 4-deep MLP)
    aggregate_w<<<NB_AG, 256, 0, stream>>>((const uint4*)hp, esrc, rowstart, cnt, dinv, b1, (uint4*)h);

    // K6/K7: layer 2
    gemm_mfma_bf16A<<<NB_G, 256, 0, stream>>>(h, W2f, dinv, hp);
    aggregate4<<<NB_AG, 256, 0, stream>>>((const uint4*)hp, esrc, rowstart, cnt, dinv, b2, (uint4*)h);

    // K8: pooling + head
    pool_head<<<N_GRAPHS, 128, 0, stream>>>(h, batch, Wlin, blin, out);
}

// Round 18
// 232.448 us; speedup vs baseline: 1.0878x; 1.0395x over previous
//
#include <hip/hip_runtime.h>

#define N_NODES 50000
#define N_PAD   50048   // 782 * 64
#define N_EDGES 800000
#define N_GRAPHS 512
#define F_IN 96
#define HID 128
#define NBUCK 196       // buckets of 256 nodes (dst >> 8)
#define CHUNK 4096      // edges per chunk block
#define NCH   196       // ceil(800000/4096)
#define NB_G 782        // gemm blocks (N_PAD/64)

typedef __bf16 bf16x8 __attribute__((ext_vector_type(8)));
typedef float  f32x4  __attribute__((ext_vector_type(4)));

__device__ __forceinline__ unsigned short f2bf(float f) {
    union { float f; unsigned u; } v; v.f = f;
    unsigned r = v.u + 0x7FFFu + ((v.u >> 16) & 1u);  // RNE
    return (unsigned short)(r >> 16);
}
__device__ __forceinline__ float bflo(unsigned u) {
    union { unsigned u; float f; } v; v.u = u << 16; return v.f;
}
__device__ __forceinline__ float bfhi(unsigned u) {
    union { unsigned u; float f; } v; v.u = u & 0xFFFF0000u; return v.f;
}

// build one B-fragment entry (8 bf16 = uint4) from f32 W[K x 128]
__device__ __forceinline__ uint4 frag_of(const float* __restrict__ W, int KS, int idx) {
    int t = idx / (KS * 64);
    int rem = idx % (KS * 64);
    int s = rem / 64;
    int l = rem & 63;
    int n = t * 16 + (l & 15);
    int k0 = s * 32 + (l >> 4) * 8;
    unsigned short v[8];
#pragma unroll
    for (int j = 0; j < 8; ++j) v[j] = f2bf(W[(long)(k0 + j) * 128 + n]);
    uint4 o;
    o.x = (unsigned)v[0] | ((unsigned)v[1] << 16);
    o.y = (unsigned)v[2] | ((unsigned)v[3] << 16);
    o.z = (unsigned)v[4] | ((unsigned)v[5] << 16);
    o.w = (unsigned)v[6] | ((unsigned)v[7] << 16);
    return o;
}

// ---- K1: gemm1-raw (0..781)  ||  chunk hists (782..977)  ||  W2 prep (978..985) ----
__global__ __launch_bounds__(256) void k1_fused(const int* __restrict__ dst,
                                                const float* __restrict__ W1,
                                                const float* __restrict__ W2,
                                                unsigned short* __restrict__ W2f,
                                                int* __restrict__ bh,
                                                const float* __restrict__ x,
                                                unsigned short* __restrict__ hp) {
    __shared__ uint4 w1lds[1536];  // 24 KB (aliased as hist for hist blocks)
    int blk = blockIdx.x;
    int tid = threadIdx.x;

    if (blk < NB_G) {
        for (int idx = tid; idx < 1536; idx += 256) w1lds[idx] = frag_of(W1, 3, idx);
        __syncthreads();

        const int KS = 3;
        const int wave = tid >> 6, lane = tid & 63;
        const int r0 = blk * 64 + wave * 16;
        f32x4 acc[8];
#pragma unroll
        for (int t = 0; t < 8; ++t) acc[t] = (f32x4){0.f, 0.f, 0.f, 0.f};
        int arow = r0 + (lane & 15);
        if (arow >= N_NODES) arow = N_NODES - 1;  // clamp; pad rows discarded on store
        const int kq = (lane >> 4) * 8;
        for (int s = 0; s < KS; ++s) {
            const float* ap = x + (long)arow * F_IN + s * 32 + kq;
            float4 a0 = *(const float4*)(ap);
            float4 a1 = *(const float4*)(ap + 4);
            union { uint4 u; bf16x8 b; } af;
            af.u.x = (unsigned)f2bf(a0.x) | ((unsigned)f2bf(a0.y) << 16);
            af.u.y = (unsigned)f2bf(a0.z) | ((unsigned)f2bf(a0.w) << 16);
            af.u.z = (unsigned)f2bf(a1.x) | ((unsigned)f2bf(a1.y) << 16);
            af.u.w = (unsigned)f2bf(a1.z) | ((unsigned)f2bf(a1.w) << 16);
#pragma unroll
            for (int t = 0; t < 8; ++t) {
                union { uint4 u; bf16x8 b; } bfr;
                bfr.u = w1lds[(t * KS + s) * 64 + lane];
                acc[t] = __builtin_amdgcn_mfma_f32_16x16x32_bf16(af.b, bfr.b, acc[t], 0, 0, 0);
            }
        }
        const int q = lane >> 4;
#pragma unroll
        for (int t = 0; t < 8; ++t) {
            int col = t * 16 + (lane & 15);
#pragma unroll
            for (int r = 0; r < 4; ++r) {
                int row = r0 + q * 4 + r;
                if (row < N_NODES) hp[(long)row * 128 + col] = f2bf(acc[t][r]);
            }
        }
    } else if (blk < NB_G + NCH) {
        int* bhist = (int*)w1lds;
        int c = blk - NB_G;
        for (int i = tid; i < NBUCK; i += 256) bhist[i] = 0;
        __syncthreads();
        int e0 = c * CHUNK, e1 = min(e0 + CHUNK, N_EDGES);
        int n4 = (e1 - e0) >> 2;  // chunk sizes divisible by 4
        const uint4* d4 = (const uint4*)(dst + e0);
        for (int i = tid; i < n4; i += 256) {
            uint4 d = d4[i];
            atomicAdd(&bhist[d.x >> 8], 1);
            atomicAdd(&bhist[d.y >> 8], 1);
            atomicAdd(&bhist[d.z >> 8], 1);
            atomicAdd(&bhist[d.w >> 8], 1);
        }
        __syncthreads();
        for (int i = tid; i < NBUCK; i += 256) bh[c * NBUCK + i] = bhist[i];
    } else {
        int idx = (blk - NB_G - NCH) * 256 + tid;  // 8 blocks x 256 = 2048 = 8*4*64
        *(uint4*)(W2f + (long)idx * 8) = frag_of(W2, 4, idx);
    }
}

// ---- K2: per-bucket scan over chunks (196 independent scans) ----
__global__ __launch_bounds__(256) void goff_scan(const int* __restrict__ bh,
                                                 int* __restrict__ goff,
                                                 int* __restrict__ total) {
    __shared__ int s[256];
    int b = blockIdx.x;
    int c = threadIdx.x;
    int v = (c < NCH) ? bh[c * NBUCK + b] : 0;
    s[c] = v;
    __syncthreads();
#pragma unroll
    for (int off = 1; off < 256; off <<= 1) {
        int t = 0;
        if (c >= off) t = s[c - off];
        __syncthreads();
        if (c >= off) s[c] += t;
        __syncthreads();
    }
    if (c < NCH) goff[c * NBUCK + b] = s[c] - v;  // exclusive (relative to bucket base)
    if (c == 255) total[b] = s[255];
}

// ---- K3: scatter pairs (PACKED: src in [0:16), local-dst in [16:24)) ----
__global__ __launch_bounds__(256) void scatter_pairs(const int* __restrict__ src,
                                                     const int* __restrict__ dst,
                                                     const int* __restrict__ goff,
                                                     const int* __restrict__ total,
                                                     unsigned* __restrict__ ebuf) {
    __shared__ int ts[256];
    __shared__ int lgoff[NBUCK];
    __shared__ int lcur[NBUCK];
    int tid = threadIdx.x;
    int c = blockIdx.x;
    int tv = (tid < NBUCK) ? total[tid] : 0;
    ts[tid] = tv;
    __syncthreads();
#pragma unroll
    for (int off = 1; off < 256; off <<= 1) {
        int t = 0;
        if (tid >= off) t = ts[tid - off];
        __syncthreads();
        if (tid >= off) ts[tid] += t;
        __syncthreads();
    }
    if (tid < NBUCK) {
        lgoff[tid] = goff[c * NBUCK + tid] + (ts[tid] - tv);  // + bstart[tid]
        lcur[tid] = 0;
    }
    __syncthreads();
    int e0 = c * CHUNK, e1 = min(e0 + CHUNK, N_EDGES);
    for (int e = e0 + tid; e < e1; e += 256) {
        int d = dst[e];
        int b = d >> 8;
        int slot = atomicAdd(&lcur[b], 1);
        ebuf[lgoff[b] + slot] = (unsigned)src[e] | ((unsigned)(d & 255) << 16);
    }
}

// ---- K4: bucket sort; unpack 32-bit entries ----
__global__ __launch_bounds__(256) void bucket_sort(const unsigned* __restrict__ ebuf,
                                                   const int* __restrict__ total,
                                                   int* __restrict__ rowstart,
                                                   int* __restrict__ cnt,
                                                   float* __restrict__ dinv,
                                                   int* __restrict__ esrc) {
    __shared__ int ts[256];
    __shared__ int lcnt[256];
    __shared__ int ssc[256];
    __shared__ int ncur[256];
    int b = blockIdx.x, tid = threadIdx.x;
    int tv = (tid < NBUCK) ? total[tid] : 0;
    ts[tid] = tv;
    __syncthreads();
#pragma unroll
    for (int off = 1; off < 256; off <<= 1) {
        int t = 0;
        if (tid >= off) t = ts[tid - off];
        __syncthreads();
        if (tid >= off) ts[tid] += t;
        __syncthreads();
    }
    int r1 = ts[b];
    int r0 = r1 - total[b];
    int nbase = b * 256;
    lcnt[tid] = 0;
    __syncthreads();
    for (int i = r0 + tid; i < r1; i += 256)
        atomicAdd(&lcnt[ebuf[i] >> 16], 1);
    __syncthreads();
    int c = lcnt[tid];
    ssc[tid] = c;
    __syncthreads();
#pragma unroll
    for (int off = 1; off < 256; off <<= 1) {
        int t = 0;
        if (tid >= off) t = ssc[tid - off];
        __syncthreads();
        if (tid >= off) ssc[tid] += t;
        __syncthreads();
    }
    int rs = r0 + ssc[tid] - c;
    ncur[tid] = rs;
    int node = nbase + tid;
    if (node < N_NODES) {
        rowstart[node] = rs;
        cnt[node] = c;
        dinv[node] = rsqrtf((float)c + 1.0f);
    }
    __syncthreads();
    for (int i = r0 + tid; i < r1; i += 256) {
        unsigned p = ebuf[i];
        int pos = atomicAdd(&ncur[p >> 16], 1);
        esrc[pos] = (int)(p & 0xFFFFu);
    }
}

// ---- K5: FUSED aggregate layer-1 + gemm layer-2 (OUTPUT TO SEPARATE BUFFER) ----
// Block = 16 nodes (grid 3125, exact). Phase A: each wave aggregates 4 nodes
// (hp raw, dinv folded, 4-deep gather) -> h1 rows in LDS (bf16, padded rows).
// Phase B: 4 waves jointly compute hp2[16 rows,128] = bf16(dinv * (h1 @ W2)).
// hp is READ-ONLY here (other blocks still gather it); hp2 is a distinct buffer.
#define H1_STRIDE 17  // uint4 per row (16 + 1 pad)
__global__ __launch_bounds__(256) void agg1_gemm2(const uint4* __restrict__ hp4,
                                                  const int* __restrict__ esrc,
                                                  const int* __restrict__ rowstart,
                                                  const int* __restrict__ cnt,
                                                  const float* __restrict__ dinv,
                                                  const float* __restrict__ b1,
                                                  const unsigned short* __restrict__ W2f,
                                                  unsigned short* __restrict__ hp2) {
    __shared__ uint4 h1[16 * H1_STRIDE];  // 4.25 KB
    const int tid = threadIdx.x;
    const int wave = tid >> 6, lane = tid & 63;
    const int eslot = lane >> 4, ug = lane & 15;
    const int nbase = blockIdx.x * 16;

    // ---- Phase A: aggregate 4 nodes per wave ----
    for (int i = 0; i < 4; ++i) {
        int node = nbase + wave * 4 + i;   // always < N_NODES (50000 = 3125*16)
        int start = rowstart[node];
        int end = start + cnt[node];

        float a[8];
#pragma unroll
        for (int k = 0; k < 8; ++k) a[k] = 0.f;

        for (int j = start; j < end; j += 16) {
            int e[4];
            uint4 v[4];
            float w[4];
#pragma unroll
            for (int q = 0; q < 4; ++q) {
                e[q] = j + q * 4 + eslot;
                int s = esrc[min(e[q], end - 1)];
                v[q] = hp4[(long)s * 16 + ug];
                w[q] = dinv[s];
            }
#pragma unroll
            for (int q = 0; q < 4; ++q) {
                if (e[q] < end) {
                    a[0] += w[q] * bflo(v[q].x); a[1] += w[q] * bfhi(v[q].x);
                    a[2] += w[q] * bflo(v[q].y); a[3] += w[q] * bfhi(v[q].y);
                    a[4] += w[q] * bflo(v[q].z); a[5] += w[q] * bfhi(v[q].z);
                    a[6] += w[q] * bflo(v[q].w); a[7] += w[q] * bfhi(v[q].w);
                }
            }
        }

#pragma unroll
        for (int k = 0; k < 8; ++k) {
            a[k] += __shfl_xor(a[k], 16);
            a[k] += __shfl_xor(a[k], 32);
        }

        if (eslot == 0) {
            float d = dinv[node];
            uint4 vs = hp4[(long)node * 16 + ug];
            a[0] += d * bflo(vs.x); a[1] += d * bfhi(vs.x);
            a[2] += d * bflo(vs.y); a[3] += d * bfhi(vs.y);
            a[4] += d * bflo(vs.z); a[5] += d * bfhi(vs.z);
            a[6] += d * bflo(vs.w); a[7] += d * bfhi(vs.w);
            float4 c0 = *(const float4*)(b1 + ug * 8);
            float4 c1 = *(const float4*)(b1 + ug * 8 + 4);
            float o0 = fmaxf(d * a[0] + c0.x, 0.f), o1 = fmaxf(d * a[1] + c0.y, 0.f);
            float o2 = fmaxf(d * a[2] + c0.z, 0.f), o3 = fmaxf(d * a[3] + c0.w, 0.f);
            float o4 = fmaxf(d * a[4] + c1.x, 0.f), o5 = fmaxf(d * a[5] + c1.y, 0.f);
            float o6 = fmaxf(d * a[6] + c1.z, 0.f), o7 = fmaxf(d * a[7] + c1.w, 0.f);
            uint4 o;
            o.x = (unsigned)f2bf(o0) | ((unsigned)f2bf(o1) << 16);
            o.y = (unsigned)f2bf(o2) | ((unsigned)f2bf(o3) << 16);
            o.z = (unsigned)f2bf(o4) | ((unsigned)f2bf(o5) << 16);
            o.w = (unsigned)f2bf(o6) | ((unsigned)f2bf(o7) << 16);
            h1[(wave * 4 + i) * H1_STRIDE + ug] = o;
        }
    }
    __syncthreads();

    // ---- Phase B: gemm2 on the 16-row LDS tile; wave owns col-tiles {wave*2, wave*2+1} ----
    const int KS = 4;
    f32x4 acc[2];
    acc[0] = (f32x4){0.f, 0.f, 0.f, 0.f};
    acc[1] = (f32x4){0.f, 0.f, 0.f, 0.f};
    const int m = lane & 15;  // local row
    for (int s = 0; s < KS; ++s) {
        union { uint4 u; bf16x8 b; } af;
        af.u = h1[m * H1_STRIDE + s * 4 + eslot];  // A[m][k=s*32+eslot*8 ..+8)
#pragma unroll
        for (int tt = 0; tt < 2; ++tt) {
            int t = wave * 2 + tt;
            union { uint4 u; bf16x8 b; } bfr;
            bfr.u = *(const uint4*)(W2f + ((long)(t * KS + s) * 64 + lane) * 8);
            acc[tt] = __builtin_amdgcn_mfma_f32_16x16x32_bf16(af.b, bfr.b, acc[tt], 0, 0, 0);
        }
    }
    const int q = lane >> 4;
    float dv[4];
#pragma unroll
    for (int r = 0; r < 4; ++r) dv[r] = dinv[nbase + q * 4 + r];
#pragma unroll
    for (int tt = 0; tt < 2; ++tt) {
        int col = (wave * 2 + tt) * 16 + (lane & 15);
#pragma unroll
        for (int r = 0; r < 4; ++r) {
            int row = nbase + q * 4 + r;
            hp2[(long)row * 128 + col] = f2bf(acc[tt][r] * dv[r]);
        }
    }
}

// ---- K6: aggregate layer 2 — hp2 pre-scaled; 4 gathers in flight ----
__global__ __launch_bounds__(256) void aggregate4(const uint4* __restrict__ hp4,
                                                  const int* __restrict__ esrc,
                                                  const int* __restrict__ rowstart,
                                                  const int* __restrict__ cnt,
                                                  const float* __restrict__ dinv,
                                                  const float* __restrict__ bias,
                                                  uint4* __restrict__ hout4) {
    int node = blockIdx.x * 4 + (threadIdx.x >> 6);
    if (node >= N_NODES) return;
    int lane = threadIdx.x & 63;
    int eslot = lane >> 4;
    int ug = lane & 15;
    int start = rowstart[node];
    int end = start + cnt[node];

    float a[8];
#pragma unroll
    for (int k = 0; k < 8; ++k) a[k] = 0.f;

    for (int j = start; j < end; j += 16) {
        int e[4];
        uint4 v[4];
#pragma unroll
        for (int q = 0; q < 4; ++q) {
            e[q] = j + q * 4 + eslot;
            int s = esrc[min(e[q], end - 1)];
            v[q] = hp4[(long)s * 16 + ug];
        }
#pragma unroll
        for (int q = 0; q < 4; ++q) {
            if (e[q] < end) {
                a[0] += bflo(v[q].x); a[1] += bfhi(v[q].x);
                a[2] += bflo(v[q].y); a[3] += bfhi(v[q].y);
                a[4] += bflo(v[q].z); a[5] += bfhi(v[q].z);
                a[6] += bflo(v[q].w); a[7] += bfhi(v[q].w);
            }
        }
    }

#pragma unroll
    for (int k = 0; k < 8; ++k) {
        a[k] += __shfl_xor(a[k], 16);
        a[k] += __shfl_xor(a[k], 32);
    }

    if (eslot == 0) {
        uint4 vs = hp4[(long)node * 16 + ug];
        a[0] += bflo(vs.x); a[1] += bfhi(vs.x);
        a[2] += bflo(vs.y); a[3] += bfhi(vs.y);
        a[4] += bflo(vs.z); a[5] += bfhi(vs.z);
        a[6] += bflo(vs.w); a[7] += bfhi(vs.w);
        float d = dinv[node];
        float4 b0 = *(const float4*)(bias + ug * 8);
        float4 b1 = *(const float4*)(bias + ug * 8 + 4);
        float o0 = fmaxf(d * a[0] + b0.x, 0.f), o1 = fmaxf(d * a[1] + b0.y, 0.f);
        float o2 = fmaxf(d * a[2] + b0.z, 0.f), o3 = fmaxf(d * a[3] + b0.w, 0.f);
        float o4 = fmaxf(d * a[4] + b1.x, 0.f), o5 = fmaxf(d * a[5] + b1.y, 0.f);
        float o6 = fmaxf(d * a[6] + b1.z, 0.f), o7 = fmaxf(d * a[7] + b1.w, 0.f);
        uint4 o;
        o.x = (unsigned)f2bf(o0) | ((unsigned)f2bf(o1) << 16);
        o.y = (unsigned)f2bf(o2) | ((unsigned)f2bf(o3) << 16);
        o.z = (unsigned)f2bf(o4) | ((unsigned)f2bf(o5) << 16);
        o.w = (unsigned)f2bf(o6) | ((unsigned)f2bf(o7) << 16);
        hout4[(long)node * 16 + ug] = o;
    }
}

// ---- K7: pooling + head ----
__global__ __launch_bounds__(128) void pool_head(const unsigned short* __restrict__ h,
                                                 const int* __restrict__ batch,
                                                 const float* __restrict__ Wlin,
                                                 const float* __restrict__ blin,
                                                 float* __restrict__ out) {
    __shared__ int bnd[2];
    int g = blockIdx.x;
    int c = threadIdx.x;
    if (c < 2) {
        int target = g + c;
        int lo = 0, hi = N_NODES;
        while (lo < hi) {
            int mid = (lo + hi) >> 1;
            if (batch[mid] < target) lo = mid + 1;
            else hi = mid;
        }
        bnd[c] = lo;
    }
    __syncthreads();
    int s = bnd[0], e = bnd[1];

    float sum = 0.f;
    for (int i = s; i < e; ++i) {
        union { unsigned u; float f; } v;
        v.u = (unsigned)h[(long)i * 128 + c] << 16;
        sum += v.f;
    }
    float inv = (e > s) ? 1.0f / (float)(e - s) : 1.0f;
    float m = sum * inv;

    __shared__ float red[128][2];
    red[c][0] = m * Wlin[c * 2 + 0];
    red[c][1] = m * Wlin[c * 2 + 1];
    __syncthreads();
#pragma unroll
    for (int off = 64; off > 0; off >>= 1) {
        if (c < off) {
            red[c][0] += red[c + off][0];
            red[c][1] += red[c + off][1];
        }
        __syncthreads();
    }
    if (c < 2) out[g * 2 + c] = red[0][c] + blin[c];
}

extern "C" void kernel_launch(void* const* d_in, const int* in_sizes, int n_in,
                              void* d_out, int out_size, void* d_ws, size_t ws_size,
                              hipStream_t stream) {
    const float* x    = (const float*)d_in[0];
    const int*   ei   = (const int*)d_in[1];
    const int*   batch= (const int*)d_in[2];
    const float* W1   = (const float*)d_in[4];
    const float* b1   = (const float*)d_in[5];
    const float* W2   = (const float*)d_in[6];
    const float* b2   = (const float*)d_in[7];
    const float* Wlin = (const float*)d_in[8];
    const float* blin = (const float*)d_in[9];
    float* out = (float*)d_out;

    const int* src = ei;
    const int* dst = ei + N_EDGES;

    char* ws = (char*)d_ws;
    const size_t KB = 1024;
    const size_t MB = 1048576;

    float*    dinv     = (float*)(ws);
    int*      cnt      = (int*)  (ws + 256 * KB);
    int*      rowstart = (int*)  (ws + 512 * KB);
    int*      total    = (int*)  (ws + 768 * KB);          // 196 ints
    int*      bh       = (int*)  (ws + 832 * KB);          // 196*196 ints
    int*      goff     = (int*)  (ws + 1 * MB);            // 196*196 ints
    unsigned* ebuf     = (unsigned*)(ws + 2 * MB);         // 3.2 MB (packed)
    int*      esrc     = (int*)  (ws + 9 * MB);            // 3.2 MB
    unsigned short* W2f = (unsigned short*)(ws + 12 * MB + 576 * KB);  // 32 KB
    unsigned short* hp  = (unsigned short*)(ws + 13 * MB);   // N_PAD x 128 bf16 (gemm1 raw, read-only after K1)
    unsigned short* hp2 = (unsigned short*)(ws + 26 * MB);   // N_PAD x 128 bf16 (fused K5 output)
    unsigned short* h   = (unsigned short*)(ws + 39 * MB);   // N_PAD x 128 bf16 (final layer-2 h)

    const int NB_AG = (N_NODES + 3) / 4;          // 12500
    const int NB_F  = N_NODES / 16;               // 3125 (exact)

    // K1: gemm1-raw || chunk hists || W2 prep
    k1_fused<<<NB_G + NCH + 8, 256, 0, stream>>>(dst, W1, W2, W2f, bh, x, hp);
    // K2: per-bucket parallel scan
    goff_scan<<<NBUCK, 256, 0, stream>>>(bh, goff, total);
    // K3/K4: scatter (packed 32-bit) + sort
    scatter_pairs<<<NCH, 256, 0, stream>>>(src, dst, goff, total, ebuf);
    bucket_sort<<<NBUCK, 256, 0, stream>>>(ebuf, total, rowstart, cnt, dinv, esrc);

    // K5: fused aggregate-1 + gemm-2 (h1 in LDS; hp read-only, hp2 separate output)
    agg1_gemm2<<<NB_F, 256, 0, stream>>>((const uint4*)hp, esrc, rowstart, cnt, dinv, b1, W2f, hp2);

    // K6: layer-2 aggregate (gathers hp2, writes h)
    aggregate4<<<NB_AG, 256, 0, stream>>>((const uint4*)hp2, esrc, rowstart, cnt, dinv, b2, (uint4*)h);

    // K7: pooling + head
    pool_head<<<N_GRAPHS, 128, 0, stream>>>(h, batch, Wlin, blin, out);
}

// Round 19
// 200.941 us; speedup vs baseline: 1.2583x; 1.1568x over previous
//
#include <hip/hip_runtime.h>

#define N_NODES 50000
#define N_PAD   50048   // 782 * 64
#define N_EDGES 800000
#define N_GRAPHS 512
#define F_IN 96
#define HID 128
#define NBUCK 196       // buckets of 256 nodes (dst >> 8)
#define CHUNK 4096      // edges per chunk block
#define NCH   196       // ceil(800000/4096)
#define NB_G 782        // gemm blocks (N_PAD/64)

typedef __bf16 bf16x8 __attribute__((ext_vector_type(8)));
typedef float  f32x4  __attribute__((ext_vector_type(4)));

__device__ __forceinline__ unsigned short f2bf(float f) {
    union { float f; unsigned u; } v; v.f = f;
    unsigned r = v.u + 0x7FFFu + ((v.u >> 16) & 1u);  // RNE
    return (unsigned short)(r >> 16);
}
__device__ __forceinline__ float bflo(unsigned u) {
    union { unsigned u; float f; } v; v.u = u << 16; return v.f;
}
__device__ __forceinline__ float bfhi(unsigned u) {
    union { unsigned u; float f; } v; v.u = u & 0xFFFF0000u; return v.f;
}

// build one B-fragment entry (8 bf16 = uint4) from f32 W[K x 128]
__device__ __forceinline__ uint4 frag_of(const float* __restrict__ W, int KS, int idx) {
    int t = idx / (KS * 64);
    int rem = idx % (KS * 64);
    int s = rem / 64;
    int l = rem & 63;
    int n = t * 16 + (l & 15);
    int k0 = s * 32 + (l >> 4) * 8;
    unsigned short v[8];
#pragma unroll
    for (int j = 0; j < 8; ++j) v[j] = f2bf(W[(long)(k0 + j) * 128 + n]);
    uint4 o;
    o.x = (unsigned)v[0] | ((unsigned)v[1] << 16);
    o.y = (unsigned)v[2] | ((unsigned)v[3] << 16);
    o.z = (unsigned)v[4] | ((unsigned)v[5] << 16);
    o.w = (unsigned)v[6] | ((unsigned)v[7] << 16);
    return o;
}

// ---- K1: gemm1-raw (0..781)  ||  chunk hists (782..977)  ||  W2 prep (978..985) ----
__global__ __launch_bounds__(256) void k1_fused(const int* __restrict__ dst,
                                                const float* __restrict__ W1,
                                                const float* __restrict__ W2,
                                                unsigned short* __restrict__ W2f,
                                                int* __restrict__ bh,
                                                const float* __restrict__ x,
                                                unsigned short* __restrict__ hp) {
    __shared__ uint4 w1lds[1536];  // 24 KB (aliased as hist for hist blocks)
    int blk = blockIdx.x;
    int tid = threadIdx.x;

    if (blk < NB_G) {
        for (int idx = tid; idx < 1536; idx += 256) w1lds[idx] = frag_of(W1, 3, idx);
        __syncthreads();

        const int KS = 3;
        const int wave = tid >> 6, lane = tid & 63;
        const int r0 = blk * 64 + wave * 16;
        f32x4 acc[8];
#pragma unroll
        for (int t = 0; t < 8; ++t) acc[t] = (f32x4){0.f, 0.f, 0.f, 0.f};
        int arow = r0 + (lane & 15);
        if (arow >= N_NODES) arow = N_NODES - 1;  // clamp; pad rows discarded on store
        const int kq = (lane >> 4) * 8;
        for (int s = 0; s < KS; ++s) {
            const float* ap = x + (long)arow * F_IN + s * 32 + kq;
            float4 a0 = *(const float4*)(ap);
            float4 a1 = *(const float4*)(ap + 4);
            union { uint4 u; bf16x8 b; } af;
            af.u.x = (unsigned)f2bf(a0.x) | ((unsigned)f2bf(a0.y) << 16);
            af.u.y = (unsigned)f2bf(a0.z) | ((unsigned)f2bf(a0.w) << 16);
            af.u.z = (unsigned)f2bf(a1.x) | ((unsigned)f2bf(a1.y) << 16);
            af.u.w = (unsigned)f2bf(a1.z) | ((unsigned)f2bf(a1.w) << 16);
#pragma unroll
            for (int t = 0; t < 8; ++t) {
                union { uint4 u; bf16x8 b; } bfr;
                bfr.u = w1lds[(t * KS + s) * 64 + lane];
                acc[t] = __builtin_amdgcn_mfma_f32_16x16x32_bf16(af.b, bfr.b, acc[t], 0, 0, 0);
            }
        }
        const int q = lane >> 4;
#pragma unroll
        for (int t = 0; t < 8; ++t) {
            int col = t * 16 + (lane & 15);
#pragma unroll
            for (int r = 0; r < 4; ++r) {
                int row = r0 + q * 4 + r;
                if (row < N_NODES) hp[(long)row * 128 + col] = f2bf(acc[t][r]);
            }
        }
    } else if (blk < NB_G + NCH) {
        int* bhist = (int*)w1lds;
        int c = blk - NB_G;
        for (int i = tid; i < NBUCK; i += 256) bhist[i] = 0;
        __syncthreads();
        int e0 = c * CHUNK, e1 = min(e0 + CHUNK, N_EDGES);
        int n4 = (e1 - e0) >> 2;  // chunk sizes divisible by 4
        const uint4* d4 = (const uint4*)(dst + e0);
        for (int i = tid; i < n4; i += 256) {
            uint4 d = d4[i];
            atomicAdd(&bhist[d.x >> 8], 1);
            atomicAdd(&bhist[d.y >> 8], 1);
            atomicAdd(&bhist[d.z >> 8], 1);
            atomicAdd(&bhist[d.w >> 8], 1);
        }
        __syncthreads();
        for (int i = tid; i < NBUCK; i += 256) bh[c * NBUCK + i] = bhist[i];
    } else {
        int idx = (blk - NB_G - NCH) * 256 + tid;  // 8 blocks x 256 = 2048 = 8*4*64
        *(uint4*)(W2f + (long)idx * 8) = frag_of(W2, 4, idx);
    }
}

// ---- K2: per-bucket scan over chunks (196 independent scans) ----
__global__ __launch_bounds__(256) void goff_scan(const int* __restrict__ bh,
                                                 int* __restrict__ goff,
                                                 int* __restrict__ total) {
    __shared__ int s[256];
    int b = blockIdx.x;
    int c = threadIdx.x;
    int v = (c < NCH) ? bh[c * NBUCK + b] : 0;
    s[c] = v;
    __syncthreads();
#pragma unroll
    for (int off = 1; off < 256; off <<= 1) {
        int t = 0;
        if (c >= off) t = s[c - off];
        __syncthreads();
        if (c >= off) s[c] += t;
        __syncthreads();
    }
    if (c < NCH) goff[c * NBUCK + b] = s[c] - v;  // exclusive (relative to bucket base)
    if (c == 255) total[b] = s[255];
}

// ---- K3: scatter pairs (PACKED: src in [0:16), local-dst in [16:24)) ----
__global__ __launch_bounds__(256) void scatter_pairs(const int* __restrict__ src,
                                                     const int* __restrict__ dst,
                                                     const int* __restrict__ goff,
                                                     const int* __restrict__ total,
                                                     unsigned* __restrict__ ebuf) {
    __shared__ int ts[256];
    __shared__ int lgoff[NBUCK];
    __shared__ int lcur[NBUCK];
    int tid = threadIdx.x;
    int c = blockIdx.x;
    int tv = (tid < NBUCK) ? total[tid] : 0;
    ts[tid] = tv;
    __syncthreads();
#pragma unroll
    for (int off = 1; off < 256; off <<= 1) {
        int t = 0;
        if (tid >= off) t = ts[tid - off];
        __syncthreads();
        if (tid >= off) ts[tid] += t;
        __syncthreads();
    }
    if (tid < NBUCK) {
        lgoff[tid] = goff[c * NBUCK + tid] + (ts[tid] - tv);  // + bstart[tid]
        lcur[tid] = 0;
    }
    __syncthreads();
    int e0 = c * CHUNK, e1 = min(e0 + CHUNK, N_EDGES);
    for (int e = e0 + tid; e < e1; e += 256) {
        int d = dst[e];
        int b = d >> 8;
        int slot = atomicAdd(&lcur[b], 1);
        ebuf[lgoff[b] + slot] = (unsigned)src[e] | ((unsigned)(d & 255) << 16);
    }
}

// ---- K4: bucket sort; unpack 32-bit entries ----
__global__ __launch_bounds__(256) void bucket_sort(const unsigned* __restrict__ ebuf,
                                                   const int* __restrict__ total,
                                                   int* __restrict__ rowstart,
                                                   int* __restrict__ cnt,
                                                   float* __restrict__ dinv,
                                                   int* __restrict__ esrc) {
    __shared__ int ts[256];
    __shared__ int lcnt[256];
    __shared__ int ssc[256];
    __shared__ int ncur[256];
    int b = blockIdx.x, tid = threadIdx.x;
    int tv = (tid < NBUCK) ? total[tid] : 0;
    ts[tid] = tv;
    __syncthreads();
#pragma unroll
    for (int off = 1; off < 256; off <<= 1) {
        int t = 0;
        if (tid >= off) t = ts[tid - off];
        __syncthreads();
        if (tid >= off) ts[tid] += t;
        __syncthreads();
    }
    int r1 = ts[b];
    int r0 = r1 - total[b];
    int nbase = b * 256;
    lcnt[tid] = 0;
    __syncthreads();
    for (int i = r0 + tid; i < r1; i += 256)
        atomicAdd(&lcnt[ebuf[i] >> 16], 1);
    __syncthreads();
    int c = lcnt[tid];
    ssc[tid] = c;
    __syncthreads();
#pragma unroll
    for (int off = 1; off < 256; off <<= 1) {
        int t = 0;
        if (tid >= off) t = ssc[tid - off];
        __syncthreads();
        if (tid >= off) ssc[tid] += t;
        __syncthreads();
    }
    int rs = r0 + ssc[tid] - c;
    ncur[tid] = rs;
    int node = nbase + tid;
    if (node < N_NODES) {
        rowstart[node] = rs;
        cnt[node] = c;
        dinv[node] = rsqrtf((float)c + 1.0f);
    }
    __syncthreads();
    for (int i = r0 + tid; i < r1; i += 256) {
        unsigned p = ebuf[i];
        int pos = atomicAdd(&ncur[p >> 16], 1);
        esrc[pos] = (int)(p & 0xFFFFu);
    }
}

// ---- K5: FUSED aggregate layer-1 + gemm layer-2 (separate output buffer) ----
#define H1_STRIDE 17  // uint4 per row (16 + 1 pad)
__global__ __launch_bounds__(256) void agg1_gemm2(const uint4* __restrict__ hp4,
                                                  const int* __restrict__ esrc,
                                                  const int* __restrict__ rowstart,
                                                  const int* __restrict__ cnt,
                                                  const float* __restrict__ dinv,
                                                  const float* __restrict__ b1,
                                                  const unsigned short* __restrict__ W2f,
                                                  unsigned short* __restrict__ hp2) {
    __shared__ uint4 h1[16 * H1_STRIDE];  // 4.25 KB
    const int tid = threadIdx.x;
    const int wave = tid >> 6, lane = tid & 63;
    const int eslot = lane >> 4, ug = lane & 15;
    const int nbase = blockIdx.x * 16;

    for (int i = 0; i < 4; ++i) {
        int node = nbase + wave * 4 + i;
        int start = rowstart[node];
        int end = start + cnt[node];

        float a[8];
#pragma unroll
        for (int k = 0; k < 8; ++k) a[k] = 0.f;

        for (int j = start; j < end; j += 16) {
            int e[4];
            uint4 v[4];
            float w[4];
#pragma unroll
            for (int q = 0; q < 4; ++q) {
                e[q] = j + q * 4 + eslot;
                int s = esrc[min(e[q], end - 1)];
                v[q] = hp4[(long)s * 16 + ug];
                w[q] = dinv[s];
            }
#pragma unroll
            for (int q = 0; q < 4; ++q) {
                if (e[q] < end) {
                    a[0] += w[q] * bflo(v[q].x); a[1] += w[q] * bfhi(v[q].x);
                    a[2] += w[q] * bflo(v[q].y); a[3] += w[q] * bfhi(v[q].y);
                    a[4] += w[q] * bflo(v[q].z); a[5] += w[q] * bfhi(v[q].z);
                    a[6] += w[q] * bflo(v[q].w); a[7] += w[q] * bfhi(v[q].w);
                }
            }
        }

#pragma unroll
        for (int k = 0; k < 8; ++k) {
            a[k] += __shfl_xor(a[k], 16);
            a[k] += __shfl_xor(a[k], 32);
        }

        if (eslot == 0) {
            float d = dinv[node];
            uint4 vs = hp4[(long)node * 16 + ug];
            a[0] += d * bflo(vs.x); a[1] += d * bfhi(vs.x);
            a[2] += d * bflo(vs.y); a[3] += d * bfhi(vs.y);
            a[4] += d * bflo(vs.z); a[5] += d * bfhi(vs.z);
            a[6] += d * bflo(vs.w); a[7] += d * bfhi(vs.w);
            float4 c0 = *(const float4*)(b1 + ug * 8);
            float4 c1 = *(const float4*)(b1 + ug * 8 + 4);
            float o0 = fmaxf(d * a[0] + c0.x, 0.f), o1 = fmaxf(d * a[1] + c0.y, 0.f);
            float o2 = fmaxf(d * a[2] + c0.z, 0.f), o3 = fmaxf(d * a[3] + c0.w, 0.f);
            float o4 = fmaxf(d * a[4] + c1.x, 0.f), o5 = fmaxf(d * a[5] + c1.y, 0.f);
            float o6 = fmaxf(d * a[6] + c1.z, 0.f), o7 = fmaxf(d * a[7] + c1.w, 0.f);
            uint4 o;
            o.x = (unsigned)f2bf(o0) | ((unsigned)f2bf(o1) << 16);
            o.y = (unsigned)f2bf(o2) | ((unsigned)f2bf(o3) << 16);
            o.z = (unsigned)f2bf(o4) | ((unsigned)f2bf(o5) << 16);
            o.w = (unsigned)f2bf(o6) | ((unsigned)f2bf(o7) << 16);
            h1[(wave * 4 + i) * H1_STRIDE + ug] = o;
        }
    }
    __syncthreads();

    const int KS = 4;
    f32x4 acc[2];
    acc[0] = (f32x4){0.f, 0.f, 0.f, 0.f};
    acc[1] = (f32x4){0.f, 0.f, 0.f, 0.f};
    const int m = lane & 15;
    for (int s = 0; s < KS; ++s) {
        union { uint4 u; bf16x8 b; } af;
        af.u = h1[m * H1_STRIDE + s * 4 + eslot];
#pragma unroll
        for (int tt = 0; tt < 2; ++tt) {
            int t = wave * 2 + tt;
            union { uint4 u; bf16x8 b; } bfr;
            bfr.u = *(const uint4*)(W2f + ((long)(t * KS + s) * 64 + lane) * 8);
            acc[tt] = __builtin_amdgcn_mfma_f32_16x16x32_bf16(af.b, bfr.b, acc[tt], 0, 0, 0);
        }
    }
    const int q = lane >> 4;
    float dv[4];
#pragma unroll
    for (int r = 0; r < 4; ++r) dv[r] = dinv[nbase + q * 4 + r];
#pragma unroll
    for (int tt = 0; tt < 2; ++tt) {
        int col = (wave * 2 + tt) * 16 + (lane & 15);
#pragma unroll
        for (int r = 0; r < 4; ++r) {
            int row = nbase + q * 4 + r;
            hp2[(long)row * 128 + col] = f2bf(acc[tt][r] * dv[r]);
        }
    }
}

// ---- K6: FUSED aggregate layer-2 + head projection ----
// Computes h[node,:] in registers, rounds to bf16 (matching the old stored-h
// numerics), dots with Wlin -> nodeS[node] = (h @ Wlin) as float2. h never
// materializes (400 KB written instead of 12.8 MB).
__global__ __launch_bounds__(256) void agg2_head(const uint4* __restrict__ hp4,
                                                 const int* __restrict__ esrc,
                                                 const int* __restrict__ rowstart,
                                                 const int* __restrict__ cnt,
                                                 const float* __restrict__ dinv,
                                                 const float* __restrict__ bias,
                                                 const float* __restrict__ Wlin,
                                                 float2* __restrict__ nodeS) {
    int node = blockIdx.x * 4 + (threadIdx.x >> 6);
    if (node >= N_NODES) return;
    int lane = threadIdx.x & 63;
    int eslot = lane >> 4;
    int ug = lane & 15;
    int start = rowstart[node];
    int end = start + cnt[node];

    float a[8];
#pragma unroll
    for (int k = 0; k < 8; ++k) a[k] = 0.f;

    for (int j = start; j < end; j += 16) {
        int e[4];
        uint4 v[4];
#pragma unroll
        for (int q = 0; q < 4; ++q) {
            e[q] = j + q * 4 + eslot;
            int s = esrc[min(e[q], end - 1)];
            v[q] = hp4[(long)s * 16 + ug];
        }
#pragma unroll
        for (int q = 0; q < 4; ++q) {
            if (e[q] < end) {
                a[0] += bflo(v[q].x); a[1] += bfhi(v[q].x);
                a[2] += bflo(v[q].y); a[3] += bfhi(v[q].y);
                a[4] += bflo(v[q].z); a[5] += bfhi(v[q].z);
                a[6] += bflo(v[q].w); a[7] += bfhi(v[q].w);
            }
        }
    }

#pragma unroll
    for (int k = 0; k < 8; ++k) {
        a[k] += __shfl_xor(a[k], 16);
        a[k] += __shfl_xor(a[k], 32);
    }

    if (eslot == 0) {
        uint4 vs = hp4[(long)node * 16 + ug];
        a[0] += bflo(vs.x); a[1] += bfhi(vs.x);
        a[2] += bflo(vs.y); a[3] += bfhi(vs.y);
        a[4] += bflo(vs.z); a[5] += bfhi(vs.z);
        a[6] += bflo(vs.w); a[7] += bfhi(vs.w);
        float d = dinv[node];
        float4 b0 = *(const float4*)(bias + ug * 8);
        float4 b1 = *(const float4*)(bias + ug * 8 + 4);
        float o[8];
        o[0] = fmaxf(d * a[0] + b0.x, 0.f); o[1] = fmaxf(d * a[1] + b0.y, 0.f);
        o[2] = fmaxf(d * a[2] + b0.z, 0.f); o[3] = fmaxf(d * a[3] + b0.w, 0.f);
        o[4] = fmaxf(d * a[4] + b1.x, 0.f); o[5] = fmaxf(d * a[5] + b1.y, 0.f);
        o[6] = fmaxf(d * a[6] + b1.z, 0.f); o[7] = fmaxf(d * a[7] + b1.w, 0.f);
#pragma unroll
        for (int k = 0; k < 8; ++k) o[k] = bflo((unsigned)f2bf(o[k]));  // keep old bf16 path
        // Wlin is [128][2] f32; lane ug owns cols ug*8..ug*8+7 -> 16 floats
        const float4* wl = (const float4*)(Wlin + ug * 16);
        float4 wA = wl[0], wB = wl[1], wC = wl[2], wD = wl[3];
        float s0 = o[0]*wA.x + o[1]*wA.z + o[2]*wB.x + o[3]*wB.z
                 + o[4]*wC.x + o[5]*wC.z + o[6]*wD.x + o[7]*wD.z;
        float s1 = o[0]*wA.y + o[1]*wA.w + o[2]*wB.y + o[3]*wB.w
                 + o[4]*wC.y + o[5]*wC.w + o[6]*wD.y + o[7]*wD.w;
        // reduce across ug lanes 0..15 (xor partners stay within 0..15, all active)
        s0 += __shfl_xor(s0, 1); s1 += __shfl_xor(s1, 1);
        s0 += __shfl_xor(s0, 2); s1 += __shfl_xor(s1, 2);
        s0 += __shfl_xor(s0, 4); s1 += __shfl_xor(s1, 4);
        s0 += __shfl_xor(s0, 8); s1 += __shfl_xor(s1, 8);
        if (ug == 0) nodeS[node] = make_float2(s0, s1);
    }
}

// ---- K7: tiny pool: out[g,:] = mean over graph of nodeS + blin ----
__global__ __launch_bounds__(256) void pool_small(const float* __restrict__ nodeSf,
                                                  const int* __restrict__ batch,
                                                  const float* __restrict__ blin,
                                                  float* __restrict__ out) {
    __shared__ int bnd[2];
    __shared__ float red[256];
    int g = blockIdx.x;
    int t = threadIdx.x;
    if (t < 2) {
        int target = g + t;
        int lo = 0, hi = N_NODES;
        while (lo < hi) {
            int mid = (lo + hi) >> 1;
            if (batch[mid] < target) lo = mid + 1;
            else hi = mid;
        }
        bnd[t] = lo;
    }
    __syncthreads();
    int s = bnd[0], e = bnd[1];
    int c = t & 1, i0 = t >> 1;  // 128 node-slots per column
    float sum = 0.f;
    for (int i = s + i0; i < e; i += 128) sum += nodeSf[i * 2 + c];
    red[t] = sum;
    __syncthreads();
#pragma unroll
    for (int off = 128; off >= 2; off >>= 1) {
        if (t < off) red[t] += red[t + off];  // same parity: off even
        __syncthreads();
    }
    if (t < 2) {
        float inv = (e > s) ? 1.0f / (float)(e - s) : 1.0f;
        out[g * 2 + t] = red[t] * inv + blin[t];
    }
}

extern "C" void kernel_launch(void* const* d_in, const int* in_sizes, int n_in,
                              void* d_out, int out_size, void* d_ws, size_t ws_size,
                              hipStream_t stream) {
    const float* x    = (const float*)d_in[0];
    const int*   ei   = (const int*)d_in[1];
    const int*   batch= (const int*)d_in[2];
    const float* W1   = (const float*)d_in[4];
    const float* b1   = (const float*)d_in[5];
    const float* W2   = (const float*)d_in[6];
    const float* b2   = (const float*)d_in[7];
    const float* Wlin = (const float*)d_in[8];
    const float* blin = (const float*)d_in[9];
    float* out = (float*)d_out;

    const int* src = ei;
    const int* dst = ei + N_EDGES;

    char* ws = (char*)d_ws;
    const size_t KB = 1024;
    const size_t MB = 1048576;

    float*    dinv     = (float*)(ws);
    int*      cnt      = (int*)  (ws + 256 * KB);
    int*      rowstart = (int*)  (ws + 512 * KB);
    int*      total    = (int*)  (ws + 768 * KB);          // 196 ints
    int*      bh       = (int*)  (ws + 832 * KB);          // 196*196 ints
    int*      goff     = (int*)  (ws + 1 * MB);            // 196*196 ints
    unsigned* ebuf     = (unsigned*)(ws + 2 * MB);         // 3.2 MB (packed)
    int*      esrc     = (int*)  (ws + 9 * MB);            // 3.2 MB
    unsigned short* W2f = (unsigned short*)(ws + 12 * MB + 576 * KB);  // 32 KB
    unsigned short* hp  = (unsigned short*)(ws + 13 * MB);   // N_PAD x 128 bf16 (gemm1 raw)
    unsigned short* hp2 = (unsigned short*)(ws + 26 * MB);   // N_PAD x 128 bf16 (K5 output)
    float2*   nodeS    = (float2*)(ws + 39 * MB);            // 50000 x 2 f32 = 400 KB

    const int NB_AG = (N_NODES + 3) / 4;          // 12500
    const int NB_F  = N_NODES / 16;               // 3125 (exact)

    // K1: gemm1-raw || chunk hists || W2 prep
    k1_fused<<<NB_G + NCH + 8, 256, 0, stream>>>(dst, W1, W2, W2f, bh, x, hp);
    // K2: per-bucket parallel scan
    goff_scan<<<NBUCK, 256, 0, stream>>>(bh, goff, total);
    // K3/K4: scatter (packed 32-bit) + sort
    scatter_pairs<<<NCH, 256, 0, stream>>>(src, dst, goff, total, ebuf);
    bucket_sort<<<NBUCK, 256, 0, stream>>>(ebuf, total, rowstart, cnt, dinv, esrc);

    // K5: fused aggregate-1 + gemm-2
    agg1_gemm2<<<NB_F, 256, 0, stream>>>((const uint4*)hp, esrc, rowstart, cnt, dinv, b1, W2f, hp2);

    // K6: fused aggregate-2 + head projection (h never materializes)
    agg2_head<<<NB_AG, 256, 0, stream>>>((const uint4*)hp2, esrc, rowstart, cnt, dinv, b2, Wlin, nodeS);

    // K7: tiny pool over 400 KB
    pool_small<<<N_GRAPHS, 256, 0, stream>>>((const float*)nodeS, batch, blin, out);
}